// Round 19
// baseline (402.431 us; speedup 1.0000x reference)
//
#include <hip/hip_runtime.h>
#include <cmath>
#include <complex>
#include <cstdio>
#include <cstring>
#include <algorithm>

#define E_EDGES 32768
#define NNODES  2048
#define VN_E    128

// ============================ host-side CG tables ============================
namespace cgt {

static double fct(int n){
  static const double f[13] = {1.,1.,2.,6.,24.,120.,720.,5040.,40320.,362880.,
                               3628800.,39916800.,479001600.};
  return f[n];
}

static double cg(int j1,int m1,int j2,int m2,int j3,int m3){
  if (m1+m2 != m3) return 0.0;
  double pre = std::sqrt((2*j3+1)*fct(j1+j2-j3)*fct(j1-j2+j3)*fct(-j1+j2+j3)/fct(j1+j2+j3+1));
  pre *= std::sqrt(fct(j3+m3)*fct(j3-m3)*fct(j1-m1)*fct(j1+m1)*fct(j2-m2)*fct(j2+m2));
  int kmin = 0;
  if (j2-j3-m1 > kmin) kmin = j2-j3-m1;
  if (j1-j3+m2 > kmin) kmin = j1-j3+m2;
  int kmax = j1+j2-j3;
  if (j1-m1 < kmax) kmax = j1-m1;
  if (j2+m2 < kmax) kmax = j2+m2;
  double s = 0.0;
  for (int k=kmin;k<=kmax;k++){
    double d = fct(k)*fct(j1+j2-j3-k)*fct(j1-m1-k)*fct(j2+m2-k)*fct(j3-j2+m1+k)*fct(j3-j1-m2+k);
    s += ((k&1)? -1.0:1.0)/d;
  }
  return pre*s;
}

typedef std::complex<double> cd;

static void umat(int l, cd U[7][7]){
  for (int a=0;a<7;a++) for (int b=0;b<7;b++) U[a][b]=cd(0,0);
  U[l][l] = cd(1,0);
  double s2 = 1.0/std::sqrt(2.0);
  for (int m=1;m<=l;m++){
    double sg = (m&1)? -1.0 : 1.0;
    U[l+m][l-m] = cd(s2,0);
    U[l+m][l+m] = cd(sg*s2,0);
    U[l-m][l-m] = cd(0, s2);
    U[l-m][l+m] = cd(0, -sg*s2);
  }
}

static bool realCoupling(int l1,int l2,int l3, double T[7][7][7]){
  cd U1[7][7],U2[7][7],U3[7][7];
  umat(l1,U1); umat(l2,U2); umat(l3,U3);
  int n1=2*l1+1, n2=2*l2+1, n3=2*l3+1;
  double Cg[7][7][7];
  for (int m=0;m<n1;m++) for(int n=0;n<n2;n++) for(int k=0;k<n3;k++)
    Cg[m][n][k] = cg(l1,m-l1,l2,n-l2,l3,k-l3);
  double Tr[7][7][7], Ti[7][7][7];
  double nr=0, ni=0;
  for (int a=0;a<n1;a++) for(int b=0;b<n2;b++) for(int c=0;c<n3;c++){
    cd s(0,0);
    for (int m=0;m<n1;m++){
      if (U1[a][m]==cd(0,0)) continue;
      for (int n=0;n<n2;n++){
        if (U2[b][n]==cd(0,0)) continue;
        for (int k=0;k<n3;k++){
          double cgv = Cg[m][n][k];
          if (cgv==0.0) continue;
          s += U1[a][m]*U2[b][n]*std::conj(U3[c][k])*cgv;
        }
      }
    }
    Tr[a][b][c]=s.real(); Ti[a][b][c]=s.imag();
    nr += s.real()*s.real(); ni += s.imag()*s.imag();
  }
  bool useR = (nr >= ni);
  double nn = std::sqrt(useR? nr : ni);
  if (nn < 1e-8) return false;
  for (int a=0;a<n1;a++)for(int b=0;b<n2;b++)for(int c=0;c<n3;c++)
    T[a][b][c] = (useR? Tr[a][b][c] : Ti[a][b][c])/nn;
  return true;
}

struct Tables {
  float val[4096];
  int   ij[4096];
  int   pmeta[40*4];
  int   ccnt[40*8];
  int   l3base[4];
  int   l3np[4];
  int   npaths;
  int   nent;
  int   tptot;
  int   pairs[256];
  float TD[256*30*8];
  int   sl_origc[40];
  int   npairs;
};

struct PathTmp {
  int l1,l2,l3, tpoff, kd;
  int ec;
  double T[7][7][7];
};

static void build(Tables& tb){
  static PathTmp paths[40];
  int np = 0, tpoff = 0;
  int l3start[5];
  for (int l3=0;l3<=3;l3++){
    tb.l3base[l3] = tpoff;
    l3start[l3] = np;
    int kd = 2*l3+1;
    for (int l1=0;l1<=3;l1++) for (int l2=0;l2<=3;l2++){
      int lo = (l1>l2)? l1-l2 : l2-l1;
      int hi = std::min(l1+l2,3);
      if (l3 < lo || l3 > hi) continue;
      PathTmp& pt = paths[np];
      if (!realCoupling(l1,l2,l3,pt.T)) continue;
      pt.l1=l1; pt.l2=l2; pt.l3=l3; pt.kd=kd; pt.tpoff=tpoff;
      double scale = std::sqrt((double)kd);
      int cnt = 0;
      for (int a=0;a<2*l1+1;a++)for(int b=0;b<2*l2+1;b++)for(int c=0;c<kd;c++)
        if (std::fabs(pt.T[a][b][c]*scale) > 1e-7) cnt++;
      pt.ec = cnt;
      tpoff += 16*kd;
      np++;
    }
  }
  l3start[4] = np;
  for (int l3=0;l3<=3;l3++) tb.l3np[l3] = l3start[l3+1]-l3start[l3];
  static int order[40];
  for (int i=0;i<np;i++) order[i]=i;
  for (int l3=0;l3<=3;l3++)
    std::sort(order+l3start[l3], order+l3start[l3+1],
              [&](int a,int b){ return paths[a].ec > paths[b].ec; });
  std::memset(tb.TD, 0, sizeof(tb.TD));
  std::memset(tb.pairs, 0, sizeof(tb.pairs));
  static int pmap[16][16];
  for (int i=0;i<16;i++) for (int j=0;j<16;j++) pmap[i][j] = -1;
  int npr = 0;
  int ep = 0;
  for (int slot=0; slot<np; slot++){
    const PathTmp& pt = paths[order[slot]];
    double scale = std::sqrt((double)pt.kd);
    int s1 = pt.l1*pt.l1, s2 = pt.l2*pt.l2;
    tb.pmeta[slot*4+0] = pt.tpoff;
    tb.pmeta[slot*4+1] = ep;
    tb.sl_origc[slot] = ((pt.tpoff - tb.l3base[pt.l3]) / (16*pt.kd)) * 16;
    int tot = 0;
    for (int c=0;c<pt.kd;c++){
      int cnt = 0;
      for (int a=0;a<2*pt.l1+1;a++)for(int b=0;b<2*pt.l2+1;b++){
        double v = pt.T[a][b][c]*scale;
        if (std::fabs(v) > 1e-7){
          tb.val[ep] = (float)v;
          tb.ij[ep]  = (s1+a) | ((s2+b)<<8);
          ep++; cnt++;
          if (pt.l3 >= 1){
            int aa = s1+a, bb = s2+b;
            int pi = pmap[aa][bb];
            if (pi < 0){ pi = npr; pmap[aa][bb] = pi;
                         tb.pairs[npr] = aa | (bb<<8); npr++; }
            tb.TD[(pi*30 + (slot-4))*8 + c] = (float)v;
          }
        }
      }
      tb.ccnt[slot*8+c] = cnt;
      tot += cnt;
    }
    for (int c=pt.kd;c<8;c++) tb.ccnt[slot*8+c]=0;
    tb.pmeta[slot*4+2] = tot;
    tb.pmeta[slot*4+3] = pt.kd;
  }
  if (npr & 1){ tb.pairs[npr] = 0; npr++; }
  tb.npairs = npr;
  tb.npaths = np; tb.nent = ep; tb.tptot = tpoff;
}

} // namespace cgt

// ============================ device kernels ============================
// LAYOUT: node/V/Vn rows are [a][m]. MFMA-path activations fp16 in HBM.
// Latent-MLP weights pre-tiled [(k/32)*N + n][32] (fragment layout, like Gtt).

typedef _Float16 half8 __attribute__((ext_vector_type(8)));
typedef __attribute__((ext_vector_type(4))) float f32x4;

__device__ inline unsigned short f2h(float f){
  union { _Float16 h; unsigned short u; } x;
  x.h = (_Float16)f;
  return x.u;
}
__device__ inline float h2f(unsigned short u){
  union { _Float16 h; unsigned short u; } x; x.u = u;
  return (float)x.h;
}

__device__ inline int swz(int row, int kh){
  int b = row*64 + kh*2;
  return b ^ (((row >> 1) & 3) << 4);
}

__device__ inline float silu(float v){ return v/(1.f+__expf(-v)); }

#define MFMA16 __builtin_amdgcn_mfma_f32_16x16x32_f16

// ---- fused two-body chain: x72 ->32->64->128->256, + [w0|w1], + V ----
__global__ __launch_bounds__(256) void tb_fused_k(
    const float* __restrict__ X72, const unsigned short* __restrict__ Wt1,
    const unsigned short* __restrict__ Wt2, const unsigned short* __restrict__ Wt3,
    const unsigned short* __restrict__ Wt4, const unsigned short* __restrict__ Wt01,
    const float* __restrict__ Yb, const float* __restrict__ envb,
    unsigned short* __restrict__ Xout, unsigned short* __restrict__ V,
    float* __restrict__ wb)
{
  __shared__ unsigned short AsB[64*32];
  __shared__ unsigned short BsB[256*32];
  __shared__ unsigned short HsA[64*264];
  __shared__ unsigned short HsB[64*264];
  __shared__ float w0s[64*16];
  const int tid  = threadIdx.x;
  const int wave = tid >> 6, lane = tid & 63;
  const int bm = blockIdx.x*64;
  const int mrow = wave*16;
  const int fr = lane & 15, fk = (lane >> 4) * 8;
  const int r4 = (lane >> 4) << 2;
  const int sra = tid >> 2, ska = (tid & 3) * 8;
  const int srb = tid >> 1, skb = (tid & 1) * 16;

  // ---- stage 1: h = silu(x72 @ W1 / sqrt(72)), N=32, K=72 (pad 96) ----
  {
    f32x4 acc[2] = {};
    for (int k0 = 0; k0 < 96; k0 += 32) {
      {
        unsigned short u[8];
        int rowg = bm + sra;
#pragma unroll
        for (int q = 0; q < 8; q++) {
          int k = k0 + ska + q;
          u[q] = (k < 72) ? f2h(X72[(size_t)rowg*72 + k]) : (unsigned short)0;
        }
        *(ushort4*)((char*)AsB + swz(sra, ska))     = *(ushort4*)&u[0];
        *(ushort4*)((char*)AsB + swz(sra, ska + 4)) = *(ushort4*)&u[4];
      }
      if (tid < 64) {
        int n = tid >> 1, kb = (tid & 1) * 16;
        unsigned short u[16];
#pragma unroll
        for (int q = 0; q < 16; q++) {
          int k = k0 + kb + q;
          u[q] = (k < 72) ? Wt1[n*72 + k] : (unsigned short)0;
        }
        *(uint4*)((char*)BsB + swz(n, kb))     = *(uint4*)&u[0];
        *(uint4*)((char*)BsB + swz(n, kb + 8)) = *(uint4*)&u[8];
      }
      __syncthreads();
      half8 af = *(half8*)((char*)AsB + swz(mrow + fr, fk));
      half8 b0 = *(half8*)((char*)BsB + swz(fr, fk));
      half8 b1 = *(half8*)((char*)BsB + swz(16 + fr, fk));
      acc[0] = MFMA16(af, b0, acc[0], 0, 0, 0);
      acc[1] = MFMA16(af, b1, acc[1], 0, 0, 0);
      __syncthreads();
    }
    const float rs = 0.11785113019775793f;
#pragma unroll
    for (int j = 0; j < 2; j++)
#pragma unroll
      for (int r = 0; r < 4; r++) {
        int row = mrow + r4 + r;
        HsA[row*264 + j*16 + fr] = f2h(silu(acc[j][r]*rs));
      }
    __syncthreads();
  }

  // ---- stage 2: h = silu(h @ W2 / sqrt(32)), N=64, K=32 ----
  {
    f32x4 acc[4] = {};
    if (tid < 128) {
      int n = tid >> 1, kb = (tid & 1) * 16;
      const unsigned short* s = Wt2 + n*32 + kb;
      uint4 u0 = *(const uint4*)s;
      uint4 u1 = *(const uint4*)(s + 8);
      *(uint4*)((char*)BsB + swz(n, kb))     = u0;
      *(uint4*)((char*)BsB + swz(n, kb + 8)) = u1;
    }
    __syncthreads();
    half8 af = *(half8*)(HsA + (mrow + fr)*264 + fk);
#pragma unroll
    for (int j = 0; j < 4; j++) {
      half8 bf = *(half8*)((char*)BsB + swz(j*16 + fr, fk));
      acc[j] = MFMA16(af, bf, acc[j], 0, 0, 0);
    }
    __syncthreads();
    const float rs = 0.17677669529663687f;
#pragma unroll
    for (int j = 0; j < 4; j++)
#pragma unroll
      for (int r = 0; r < 4; r++) {
        int row = mrow + r4 + r;
        HsB[row*264 + j*16 + fr] = f2h(silu(acc[j][r]*rs));
      }
    __syncthreads();
  }

  // ---- stage 3: h = silu(h @ W3 / 8), N=128, K=64 ----
  {
    f32x4 acc[8] = {};
    for (int k0 = 0; k0 < 64; k0 += 32) {
      {
        int n = srb, kb = skb;
        const unsigned short* s = Wt3 + n*64 + k0 + kb;
        uint4 u0 = *(const uint4*)s;
        uint4 u1 = *(const uint4*)(s + 8);
        *(uint4*)((char*)BsB + swz(n, kb))     = u0;
        *(uint4*)((char*)BsB + swz(n, kb + 8)) = u1;
      }
      __syncthreads();
      half8 af = *(half8*)(HsB + (mrow + fr)*264 + k0 + fk);
#pragma unroll
      for (int j = 0; j < 8; j++) {
        half8 bf = *(half8*)((char*)BsB + swz(j*16 + fr, fk));
        acc[j] = MFMA16(af, bf, acc[j], 0, 0, 0);
      }
      __syncthreads();
    }
    const float rs = 0.125f;
#pragma unroll
    for (int j = 0; j < 8; j++)
#pragma unroll
      for (int r = 0; r < 4; r++) {
        int row = mrow + r4 + r;
        HsA[row*264 + j*16 + fr] = f2h(silu(acc[j][r]*rs));
      }
    __syncthreads();
  }

  // ---- stage 4: x = env * (h @ W4 / sqrt(128)), N=256, K=128 ----
  {
    f32x4 acc[16] = {};
    for (int k0 = 0; k0 < 128; k0 += 32) {
#pragma unroll
      for (int h = 0; h < 2; h++) {
        int n = h*128 + srb;
        const unsigned short* s = Wt4 + (size_t)n*128 + k0 + skb;
        uint4 u0 = *(const uint4*)s;
        uint4 u1 = *(const uint4*)(s + 8);
        *(uint4*)((char*)BsB + swz(n, skb))     = u0;
        *(uint4*)((char*)BsB + swz(n, skb + 8)) = u1;
      }
      __syncthreads();
      half8 af = *(half8*)(HsA + (mrow + fr)*264 + k0 + fk);
#pragma unroll
      for (int j = 0; j < 16; j++) {
        half8 bf = *(half8*)((char*)BsB + swz(j*16 + fr, fk));
        acc[j] = MFMA16(af, bf, acc[j], 0, 0, 0);
      }
      __syncthreads();
    }
    const float rs = 0.08838834764831845f;
#pragma unroll
    for (int j = 0; j < 16; j++)
#pragma unroll
      for (int r = 0; r < 4; r++) {
        int row = mrow + r4 + r;
        float v = acc[j][r]*rs*envb[bm + row];
        unsigned short hv = f2h(v);
        HsB[row*264 + j*16 + fr] = hv;
        Xout[((size_t)(bm + row))*256 + j*16 + fr] = hv;
      }
    __syncthreads();
  }

  // ---- stage 5: [w0|w1] = x @ [W0|W1] / 16, N=32, K=256 ----
  {
    f32x4 acc[2] = {};
    for (int k0 = 0; k0 < 256; k0 += 32) {
      if (tid < 64) {
        int n = tid >> 1, kb = (tid & 1) * 16;
        const unsigned short* s = Wt01 + (size_t)n*256 + k0 + kb;
        uint4 u0 = *(const uint4*)s;
        uint4 u1 = *(const uint4*)(s + 8);
        *(uint4*)((char*)BsB + swz(n, kb))     = u0;
        *(uint4*)((char*)BsB + swz(n, kb + 8)) = u1;
      }
      __syncthreads();
      half8 af = *(half8*)(HsB + (mrow + fr)*264 + k0 + fk);
      half8 b0 = *(half8*)((char*)BsB + swz(fr, fk));
      half8 b1 = *(half8*)((char*)BsB + swz(16 + fr, fk));
      acc[0] = MFMA16(af, b0, acc[0], 0, 0, 0);
      acc[1] = MFMA16(af, b1, acc[1], 0, 0, 0);
      __syncthreads();
    }
#pragma unroll
    for (int r = 0; r < 4; r++) {
      int row = mrow + r4 + r;
      w0s[row*16 + fr] = acc[0][r]*0.0625f;
      wb[((size_t)(bm + row))*16 + fr] = acc[1][r]*0.0625f;
    }
    __syncthreads();
  }

  // ---- V init ----
  for (int i = tid; i < 64*256; i += 256) {
    int e = i >> 8, idx = i & 255;
    V[(((size_t)(bm + e)) << 8) + idx] =
        f2h(w0s[e*16 + (idx & 15)] * Yb[(bm + e)*16 + (idx >> 4)]);
  }
}

// ---- fused 3-layer latent MLP v3 (R19): barrier-free k-loops ----
// B-operands read directly from L2 in fragment-tiled layout (like vn_k's Gtt),
// 1-step register prefetch; A from global (stage 1) or Hs (stages 2-4).
// Barriers only at stage boundaries (6 total vs ~52 in v2).
// MODE 0: writes x_new + w2 -> wb.  MODE 1: in-LDS head -> outE.
template<int MODE>
__global__ __launch_bounds__(512) void mlp3_k(
    const unsigned short* __restrict__ X, const unsigned short* __restrict__ T0,
    const unsigned short* __restrict__ W1t, const unsigned short* __restrict__ W2t,
    const unsigned short* __restrict__ W3t, unsigned short* __restrict__ Out,
    const float* __restrict__ env, const float* __restrict__ alphap,
    const unsigned short* __restrict__ Wtw2, float* __restrict__ wb,
    const float* __restrict__ Wh, const float* __restrict__ Wout,
    float* __restrict__ outE)
{
  __shared__ unsigned short Hs[128*264];    // 67.6 KB
  __shared__ float hcs[256];
  __shared__ float red[512];
  const int tid  = threadIdx.x;
  const int wave = tid >> 6, lane = tid & 63;
  const int bm = blockIdx.x*128;
  const int rowh = (wave >> 2)*64;
  const int wc = (wave & 3)*64;
  const int fr = lane & 15, fk = (lane >> 4) * 8;
  const int r4 = (lane >> 4) << 2;
  if (MODE == 1 && tid < 256) {
    float s = 0.f;
#pragma unroll 16
    for (int j = 0; j < 128; j++) s += Wh[tid*128 + j] * Wout[j];
    hcs[tid] = s;
  }
  f32x4 acc[4][4] = {};

  // ---- stage 1: h1 = silu([x|tp0] @ W1 / sqrt(320)), 10 steps, no barriers ----
  {
    const unsigned short* bp = W1t + ((size_t)(wc + fr))*32 + fk;
    // A-frag loader: row = bm+rowh+i*16+fr, k = k0+fk
    #define LDA1(i,k0) (*((const half8*)(((k0)+fk < 256) \
        ? X  + (size_t)(bm + rowh + (i)*16 + fr)*256 + (k0) + fk \
        : T0 + (size_t)(bm + rowh + (i)*16 + fr)*64  + (k0) + fk - 256)))
    half8 a0 = LDA1(0,0), a1 = LDA1(1,0), a2 = LDA1(2,0), a3 = LDA1(3,0);
    half8 b0 = *(const half8*)(bp);
    half8 b1 = *(const half8*)(bp + 512);
    half8 b2 = *(const half8*)(bp + 1024);
    half8 b3 = *(const half8*)(bp + 1536);
    for (int sl = 0; sl < 10; sl++) {
      half8 na0, na1, na2, na3, nb0, nb1, nb2, nb3;
      if (sl + 1 < 10) {
        int k0n = (sl + 1)*32;
        na0 = LDA1(0,k0n); na1 = LDA1(1,k0n); na2 = LDA1(2,k0n); na3 = LDA1(3,k0n);
        const unsigned short* bn = bp + (size_t)(sl + 1)*8192;
        nb0 = *(const half8*)(bn);
        nb1 = *(const half8*)(bn + 512);
        nb2 = *(const half8*)(bn + 1024);
        nb3 = *(const half8*)(bn + 1536);
      } else { na0=a0; na1=a1; na2=a2; na3=a3; nb0=b0; nb1=b1; nb2=b2; nb3=b3; }
      acc[0][0] = MFMA16(a0, b0, acc[0][0], 0, 0, 0);
      acc[1][0] = MFMA16(a1, b0, acc[1][0], 0, 0, 0);
      acc[2][0] = MFMA16(a2, b0, acc[2][0], 0, 0, 0);
      acc[3][0] = MFMA16(a3, b0, acc[3][0], 0, 0, 0);
      acc[0][1] = MFMA16(a0, b1, acc[0][1], 0, 0, 0);
      acc[1][1] = MFMA16(a1, b1, acc[1][1], 0, 0, 0);
      acc[2][1] = MFMA16(a2, b1, acc[2][1], 0, 0, 0);
      acc[3][1] = MFMA16(a3, b1, acc[3][1], 0, 0, 0);
      acc[0][2] = MFMA16(a0, b2, acc[0][2], 0, 0, 0);
      acc[1][2] = MFMA16(a1, b2, acc[1][2], 0, 0, 0);
      acc[2][2] = MFMA16(a2, b2, acc[2][2], 0, 0, 0);
      acc[3][2] = MFMA16(a3, b2, acc[3][2], 0, 0, 0);
      acc[0][3] = MFMA16(a0, b3, acc[0][3], 0, 0, 0);
      acc[1][3] = MFMA16(a1, b3, acc[1][3], 0, 0, 0);
      acc[2][3] = MFMA16(a2, b3, acc[2][3], 0, 0, 0);
      acc[3][3] = MFMA16(a3, b3, acc[3][3], 0, 0, 0);
      a0=na0; a1=na1; a2=na2; a3=na3; b0=nb0; b1=nb1; b2=nb2; b3=nb3;
    }
    #undef LDA1
  }
  const float rs320 = 0.055901699437494740f;
#pragma unroll
  for (int i = 0; i < 4; i++)
#pragma unroll
    for (int r = 0; r < 4; r++) {
      int row = rowh + i*16 + r4 + r;
#pragma unroll
      for (int j = 0; j < 4; j++) {
        Hs[row*264 + wc + j*16 + fr] = f2h(silu(acc[i][j][r]*rs320));
        acc[i][j][r] = 0.f;
      }
    }
  __syncthreads();

  // ---- stage 2: h2 = silu(h1 @ W2 / 16), 8 steps, no barriers ----
  {
    const unsigned short* bp = W2t + ((size_t)(wc + fr))*32 + fk;
    half8 b0 = *(const half8*)(bp);
    half8 b1 = *(const half8*)(bp + 512);
    half8 b2 = *(const half8*)(bp + 1024);
    half8 b3 = *(const half8*)(bp + 1536);
    for (int sl = 0; sl < 8; sl++) {
      half8 nb0, nb1, nb2, nb3;
      if (sl + 1 < 8) {
        const unsigned short* bn = bp + (size_t)(sl + 1)*8192;
        nb0 = *(const half8*)(bn);
        nb1 = *(const half8*)(bn + 512);
        nb2 = *(const half8*)(bn + 1024);
        nb3 = *(const half8*)(bn + 1536);
      } else { nb0=b0; nb1=b1; nb2=b2; nb3=b3; }
      int k0 = sl*32;
      half8 a0 = *(half8*)(Hs + (rowh +  0 + fr)*264 + k0 + fk);
      half8 a1 = *(half8*)(Hs + (rowh + 16 + fr)*264 + k0 + fk);
      half8 a2 = *(half8*)(Hs + (rowh + 32 + fr)*264 + k0 + fk);
      half8 a3 = *(half8*)(Hs + (rowh + 48 + fr)*264 + k0 + fk);
      acc[0][0] = MFMA16(a0, b0, acc[0][0], 0, 0, 0);
      acc[1][0] = MFMA16(a1, b0, acc[1][0], 0, 0, 0);
      acc[2][0] = MFMA16(a2, b0, acc[2][0], 0, 0, 0);
      acc[3][0] = MFMA16(a3, b0, acc[3][0], 0, 0, 0);
      acc[0][1] = MFMA16(a0, b1, acc[0][1], 0, 0, 0);
      acc[1][1] = MFMA16(a1, b1, acc[1][1], 0, 0, 0);
      acc[2][1] = MFMA16(a2, b1, acc[2][1], 0, 0, 0);
      acc[3][1] = MFMA16(a3, b1, acc[3][1], 0, 0, 0);
      acc[0][2] = MFMA16(a0, b2, acc[0][2], 0, 0, 0);
      acc[1][2] = MFMA16(a1, b2, acc[1][2], 0, 0, 0);
      acc[2][2] = MFMA16(a2, b2, acc[2][2], 0, 0, 0);
      acc[3][2] = MFMA16(a3, b2, acc[3][2], 0, 0, 0);
      acc[0][3] = MFMA16(a0, b3, acc[0][3], 0, 0, 0);
      acc[1][3] = MFMA16(a1, b3, acc[1][3], 0, 0, 0);
      acc[2][3] = MFMA16(a2, b3, acc[2][3], 0, 0, 0);
      acc[3][3] = MFMA16(a3, b3, acc[3][3], 0, 0, 0);
      b0=nb0; b1=nb1; b2=nb2; b3=nb3;
    }
  }
  __syncthreads();   // all reads of h1 done before overwrite
#pragma unroll
  for (int i = 0; i < 4; i++)
#pragma unroll
    for (int r = 0; r < 4; r++) {
      int row = rowh + i*16 + r4 + r;
#pragma unroll
      for (int j = 0; j < 4; j++) {
        Hs[row*264 + wc + j*16 + fr] = f2h(silu(acc[i][j][r]*0.0625f));
        acc[i][j][r] = 0.f;
      }
    }
  __syncthreads();

  // ---- stage 3: x_new = resid(env * (h2 @ W3 / 16)), 8 steps, no barriers ----
  {
    const unsigned short* bp = W3t + ((size_t)(wc + fr))*32 + fk;
    half8 b0 = *(const half8*)(bp);
    half8 b1 = *(const half8*)(bp + 512);
    half8 b2 = *(const half8*)(bp + 1024);
    half8 b3 = *(const half8*)(bp + 1536);
    for (int sl = 0; sl < 8; sl++) {
      half8 nb0, nb1, nb2, nb3;
      if (sl + 1 < 8) {
        const unsigned short* bn = bp + (size_t)(sl + 1)*8192;
        nb0 = *(const half8*)(bn);
        nb1 = *(const half8*)(bn + 512);
        nb2 = *(const half8*)(bn + 1024);
        nb3 = *(const half8*)(bn + 1536);
      } else { nb0=b0; nb1=b1; nb2=b2; nb3=b3; }
      int k0 = sl*32;
      half8 a0 = *(half8*)(Hs + (rowh +  0 + fr)*264 + k0 + fk);
      half8 a1 = *(half8*)(Hs + (rowh + 16 + fr)*264 + k0 + fk);
      half8 a2 = *(half8*)(Hs + (rowh + 32 + fr)*264 + k0 + fk);
      half8 a3 = *(half8*)(Hs + (rowh + 48 + fr)*264 + k0 + fk);
      acc[0][0] = MFMA16(a0, b0, acc[0][0], 0, 0, 0);
      acc[1][0] = MFMA16(a1, b0, acc[1][0], 0, 0, 0);
      acc[2][0] = MFMA16(a2, b0, acc[2][0], 0, 0, 0);
      acc[3][0] = MFMA16(a3, b0, acc[3][0], 0, 0, 0);
      acc[0][1] = MFMA16(a0, b1, acc[0][1], 0, 0, 0);
      acc[1][1] = MFMA16(a1, b1, acc[1][1], 0, 0, 0);
      acc[2][1] = MFMA16(a2, b1, acc[2][1], 0, 0, 0);
      acc[3][1] = MFMA16(a3, b1, acc[3][1], 0, 0, 0);
      acc[0][2] = MFMA16(a0, b2, acc[0][2], 0, 0, 0);
      acc[1][2] = MFMA16(a1, b2, acc[1][2], 0, 0, 0);
      acc[2][2] = MFMA16(a2, b2, acc[2][2], 0, 0, 0);
      acc[3][2] = MFMA16(a3, b2, acc[3][2], 0, 0, 0);
      acc[0][3] = MFMA16(a0, b3, acc[0][3], 0, 0, 0);
      acc[1][3] = MFMA16(a1, b3, acc[1][3], 0, 0, 0);
      acc[2][3] = MFMA16(a2, b3, acc[2][3], 0, 0, 0);
      acc[3][3] = MFMA16(a3, b3, acc[3][3], 0, 0, 0);
      b0=nb0; b1=nb1; b2=nb2; b3=nb3;
    }
  }
  __syncthreads();
  {
    float al = alphap[0];
    float a2 = al*al, inv1a2 = 1.f/(1.f+a2);
#pragma unroll
    for (int i = 0; i < 4; i++)
#pragma unroll
      for (int r = 0; r < 4; r++) {
        int row = rowh + i*16 + r4 + r;
        int grow = bm + row;
        float ev = env[grow];
#pragma unroll
        for (int j = 0; j < 4; j++) {
          int col = wc + j*16 + fr;
          float v = acc[i][j][r]*0.0625f*ev;
          v = (h2f(X[(size_t)grow*256 + col]) + a2*v)*inv1a2;
          unsigned short hv = f2h(v);
          Hs[row*264 + col] = hv;
          if (MODE == 0) Out[(size_t)grow*256 + col] = hv;
        }
      }
  }
  __syncthreads();

  if (MODE == 0) {
    // ---- stage 4: w2 = x_new @ W_w2 / 16 (tiled, N=16), waves wc==0 only ----
    if ((wave & 3) == 0) {
      f32x4 acc2[4] = {};
      const unsigned short* bp = Wtw2 + ((size_t)fr)*32 + fk;
      half8 bf = *(const half8*)(bp);
      for (int sl = 0; sl < 8; sl++) {
        half8 nbf = (sl + 1 < 8) ? *(const half8*)(bp + (size_t)(sl + 1)*512) : bf;
        int k0 = sl*32;
#pragma unroll
        for (int i = 0; i < 4; i++) {
          half8 af = *(half8*)(Hs + (rowh + i*16 + fr)*264 + k0 + fk);
          acc2[i] = MFMA16(af, bf, acc2[i], 0, 0, 0);
        }
        bf = nbf;
      }
#pragma unroll
      for (int i = 0; i < 4; i++)
#pragma unroll
        for (int r = 0; r < 4; r++)
          wb[((size_t)(bm + rowh + i*16 + r4 + r))*16 + fr] = acc2[i][r]*0.0625f;
    }
  } else {
    // ---- final head: out[e] = env * dot(x_new, hc) / (16*sqrt(128)) ----
    int row = tid >> 2, q = tid & 3;
    float p = 0.f;
#pragma unroll 16
    for (int c = q*64; c < q*64 + 64; c++)
      p += h2f(Hs[row*264 + c]) * hcs[c];
    red[tid] = p;
    __syncthreads();
    if (q == 0) {
      float t = red[tid] + red[tid+1] + red[tid+2] + red[tid+3];
      outE[bm + row] = env[bm + row]*t*0.0055242717280199023f;
    }
  }
}

// ---- fused Vn kernel + layer-1 tp0 ----
__global__ __launch_bounds__(512) void vn_k(
    const float* __restrict__ node, const unsigned short* __restrict__ V,
    const int* __restrict__ senders, const float* __restrict__ varepsp,
    const int* __restrict__ pairsG, const unsigned short* __restrict__ Gtt,
    unsigned short* __restrict__ Vn, int Kdim,
    const int* __restrict__ pmeta, const int* __restrict__ entIJ,
    const float* __restrict__ entVal, unsigned short* __restrict__ tp0)
{
  __shared__ unsigned short Ab[VN_E*264];
  __shared__ unsigned short Bb[VN_E*264];
  __shared__ int Ps[256];
  const int tid = threadIdx.x;
  const int e0 = blockIdx.x * VN_E;
  const int wave = tid >> 6, lane = tid & 63;
  float ve = varepsp[0];
  float eps = rsqrtf(1.f + ve*ve);
  if (tid < 256) Ps[tid] = pairsG[tid];
#pragma unroll
  for (int rr = 0; rr < 16; rr++) {
    int row = wave*16 + rr;
    int s = senders[e0 + row];
    float4 fa = *(const float4*)(node + ((size_t)s << 8) + 4*lane);
    uint2 ub = *(const uint2*)(V + (((size_t)(e0 + row)) << 8) + 4*lane);
    unsigned short* ad = Ab + row*264 + 4*lane;
    unsigned short* bd = Bb + row*264 + 4*lane;
    uint2 ua;
    ua.x = (unsigned)f2h(fa.x*eps) | ((unsigned)f2h(fa.y*eps) << 16);
    ua.y = (unsigned)f2h(fa.z*eps) | ((unsigned)f2h(fa.w*eps) << 16);
    *(uint2*)ad = ua;
    *(uint2*)bd = ub;
  }
  __syncthreads();
  for (int o = tid; o < VN_E*64; o += 512) {
    int e = o >> 6, c = o & 63;
    int p = c >> 4, m = c & 15;
    const unsigned short* Ae = Ab + e*264;
    const unsigned short* Be = Bb + e*264;
    int es = pmeta[p*4+1], ec = pmeta[p*4+2];
    float acc = 0.f;
    for (int t = 0; t < ec; t++) {
      int ij = entIJ[es+t];
      acc += entVal[es+t] * h2f(Ae[((ij&255)<<4)+m]) * h2f(Be[(((ij>>8)&255)<<4)+m]);
    }
    tp0[((size_t)(e0+e)<<6) + pmeta[p*4+0] + m] = f2h(acc);
  }
  const int rowb = (wave & 1) * 64;
  const int wc   = (wave >> 1) * 64;
  const int fr = lane & 15, fk = (lane >> 4) * 8;
  const int pairSel = fk >> 4;
  const int moff = fk & 15;
  const int nslab = Kdim >> 5;
  f32x4 acc[4][4] = {};

  const unsigned short* Ar0 = Ab + (rowb + fr)*264;
  const unsigned short* Br0 = Bb + (rowb + fr)*264;
  const unsigned short* Ar1 = Ab + (rowb + 16 + fr)*264;
  const unsigned short* Br1 = Bb + (rowb + 16 + fr)*264;
  const unsigned short* Ar2 = Ab + (rowb + 32 + fr)*264;
  const unsigned short* Br2 = Bb + (rowb + 32 + fr)*264;
  const unsigned short* Ar3 = Ab + (rowb + 48 + fr)*264;
  const unsigned short* Br3 = Bb + (rowb + 48 + fr)*264;

  const unsigned short* gp = Gtt + ((size_t)(wc + fr)) * 32 + fk;
  half8 b0 = *(const half8*)(gp);
  half8 b1 = *(const half8*)(gp + 512);
  half8 b2 = *(const half8*)(gp + 1024);
  half8 b3 = *(const half8*)(gp + 1536);
  half8 c0 = b0, c1 = b1, c2 = b2, c3 = b3;
  if (nslab > 1) {
    const unsigned short* g1 = gp + 8192;
    c0 = *(const half8*)(g1);
    c1 = *(const half8*)(g1 + 512);
    c2 = *(const half8*)(g1 + 1024);
    c3 = *(const half8*)(g1 + 1536);
  }
  int p0 = Ps[pairSel];
  int aoff = ((p0 & 255) << 4) + moff;
  int boff = (((p0 >> 8) & 255) << 4) + moff;
  half8 rA0 = *(const half8*)(Ar0 + aoff);
  half8 rB0 = *(const half8*)(Br0 + boff);
  half8 rA1 = *(const half8*)(Ar1 + aoff);
  half8 rB1 = *(const half8*)(Br1 + boff);
  half8 rA2 = *(const half8*)(Ar2 + aoff);
  half8 rB2 = *(const half8*)(Br2 + boff);
  half8 rA3 = *(const half8*)(Ar3 + aoff);
  half8 rB3 = *(const half8*)(Br3 + boff);

  for (int sl = 0; sl < nslab; sl++) {
    half8 a0 = rA0 * rB0;
    half8 a1 = rA1 * rB1;
    half8 a2 = rA2 * rB2;
    half8 a3 = rA3 * rB3;
    if (sl + 1 < nslab) {
      int pn = Ps[2*(sl + 1) + pairSel];
      int aoffn = ((pn & 255) << 4) + moff;
      int boffn = (((pn >> 8) & 255) << 4) + moff;
      rA0 = *(const half8*)(Ar0 + aoffn);
      rB0 = *(const half8*)(Br0 + boffn);
      rA1 = *(const half8*)(Ar1 + aoffn);
      rB1 = *(const half8*)(Br1 + boffn);
      rA2 = *(const half8*)(Ar2 + aoffn);
      rB2 = *(const half8*)(Br2 + boffn);
      rA3 = *(const half8*)(Ar3 + aoffn);
      rB3 = *(const half8*)(Br3 + boffn);
    }
    half8 d0, d1, d2, d3;
    if (sl + 2 < nslab) {
      const unsigned short* gn = gp + (size_t)(sl + 2) * 8192;
      d0 = *(const half8*)(gn);
      d1 = *(const half8*)(gn + 512);
      d2 = *(const half8*)(gn + 1024);
      d3 = *(const half8*)(gn + 1536);
    } else { d0 = c0; d1 = c1; d2 = c2; d3 = c3; }
    acc[0][0] = MFMA16(a0, b0, acc[0][0], 0, 0, 0);
    acc[1][0] = MFMA16(a1, b0, acc[1][0], 0, 0, 0);
    acc[2][0] = MFMA16(a2, b0, acc[2][0], 0, 0, 0);
    acc[3][0] = MFMA16(a3, b0, acc[3][0], 0, 0, 0);
    acc[0][1] = MFMA16(a0, b1, acc[0][1], 0, 0, 0);
    acc[1][1] = MFMA16(a1, b1, acc[1][1], 0, 0, 0);
    acc[2][1] = MFMA16(a2, b1, acc[2][1], 0, 0, 0);
    acc[3][1] = MFMA16(a3, b1, acc[3][1], 0, 0, 0);
    acc[0][2] = MFMA16(a0, b2, acc[0][2], 0, 0, 0);
    acc[1][2] = MFMA16(a1, b2, acc[1][2], 0, 0, 0);
    acc[2][2] = MFMA16(a2, b2, acc[2][2], 0, 0, 0);
    acc[3][2] = MFMA16(a3, b2, acc[3][2], 0, 0, 0);
    acc[0][3] = MFMA16(a0, b3, acc[0][3], 0, 0, 0);
    acc[1][3] = MFMA16(a1, b3, acc[1][3], 0, 0, 0);
    acc[2][3] = MFMA16(a2, b3, acc[2][3], 0, 0, 0);
    acc[3][3] = MFMA16(a3, b3, acc[3][3], 0, 0, 0);
    b0 = c0; b1 = c1; b2 = c2; b3 = c3;
    c0 = d0; c1 = d1; c2 = d2; c3 = d3;
  }
  const int r4 = (lane >> 4) << 2;
#pragma unroll
  for (int rg = 0; rg < 4; rg++) {
#pragma unroll
    for (int j = 0; j < 4; j++) {
#pragma unroll
      for (int r = 0; r < 4; r++) {
        int row = e0 + rowb + rg*16 + r4 + r;
        int col = wc + j*16 + fr;
        Vn[(size_t)row*256 + col] = f2h(acc[rg][j][r]);
      }
    }
  }
}

// ---- Gtt[slab][col][32] = coupling x Wv (fp16, tiled). col = kabs*16+d ----
__global__ void gbuild_k(const float* __restrict__ TD,
    const float* __restrict__ Wv1, const float* __restrict__ Wv2,
    const float* __restrict__ Wv3, const int* __restrict__ sl_origc,
    unsigned short* __restrict__ Gt, int Kdim, int npairs,
    int s1b, int s1e, int s2e, int s3e)
{
  int k = blockIdx.x*256 + threadIdx.x;
  if (k >= Kdim) return;
  int col = blockIdx.y;
  int pair = k >> 4, m = k & 15;
  int d = col & 15, kabs = col >> 4;
  float acc = 0.f;
  if (kabs > 0 && pair < npairs) {
    const float* Wv; int ss, se, kloc;
    if (kabs < 4)      { Wv = Wv1; ss = s1b; se = s1e; kloc = kabs - 1; }
    else if (kabs < 9) { Wv = Wv2; ss = s1e; se = s2e; kloc = kabs - 4; }
    else               { Wv = Wv3; ss = s2e; se = s3e; kloc = kabs - 9; }
    for (int slot = ss; slot < se; slot++)
      acc += TD[((pair*30) + (slot - 4))*8 + kloc] * Wv[(sl_origc[slot] + m)*16 + d];
    acc *= rsqrtf((float)(16*(se - ss)));
  }
  Gt[((size_t)((k >> 5)*256 + col))*32 + (k & 31)] = f2h(acc);
}

// ---- weight convert + transpose: Wt[n][k] = fp16(W[k][n]) (row-major) ----
struct WDesc { const float* src; unsigned short* dst; int K; int lgN; };
struct WPack { WDesc d[4]; };
__global__ void wcvt_k(WPack p){
  WDesc d = p.d[blockIdx.y];
  int total = d.K << d.lgN;
  int gid = blockIdx.x*256 + threadIdx.x;
  if (gid >= total) return;
  int k = gid >> d.lgN, n = gid & ((1 << d.lgN) - 1);
  d.dst[(size_t)n*d.K + k] = f2h(d.src[gid]);
}

// ---- tiled convert: dst[((k/32)*N + n)*32 + k%32] = fp16(W[k][n]) ----
struct WPackT { WDesc d[7]; };
__global__ void wcvt_tile_k(WPackT p){
  WDesc d = p.d[blockIdx.y];
  int total = d.K << d.lgN;
  int gid = blockIdx.x*256 + threadIdx.x;
  if (gid >= total) return;
  int k = gid >> d.lgN, n = gid & ((1 << d.lgN) - 1);
  d.dst[(((size_t)(k >> 5) << d.lgN) + n)*32 + (k & 31)] = f2h(d.src[gid]);
}

// ---- Wt01[n][k]: n<16 -> W0[k][n]; n>=16 -> W1[k][n-16] ----
__global__ void wcvt01_k(const float* __restrict__ W0, const float* __restrict__ W1,
                         unsigned short* __restrict__ dst){
  int gid = blockIdx.x*256 + threadIdx.x;
  int k = gid >> 5, n = gid & 31;
  float v = (n < 16) ? W0[k*16 + n] : W1[k*16 + (n - 16)];
  dst[(size_t)n*256 + k] = f2h(v);
}

__global__ void edge_init_k(const float* __restrict__ vectors, const int* __restrict__ senders,
    const int* __restrict__ receivers, const int* __restrict__ species,
    const float* __restrict__ emb, float* __restrict__ envb, float* __restrict__ Yb,
    float* __restrict__ x72)
{
  const int e = blockIdx.x*256 + threadIdx.x;
  float vx = vectors[e*3+0], vy = vectors[e*3+1], vz = vectors[e*3+2];
  float d = sqrtf(vx*vx+vy*vy+vz*vz);
  float dd = (d==0.f) ? 1.f : d;
  float invd = 1.f/dd;
  float x = vx*invd, y = vy*invd, z = vz*invd;
  float d2=d*d, d3=d2*d, d6=d3*d3, d7=d6*d, d8=d7*d;
  float envv = (d<1.f) ? (1.f - 28.f*d6 + 48.f*d7 - 21.f*d8) : 0.f;
  envb[e] = envv;
  float mask = (d==0.f)?0.f:1.f;
  const float SQ2 = 1.41421356237309515f;
  const float PIf = 3.14159265358979323846f;
  float* xr = x72 + (size_t)e*72;
#pragma unroll
  for (int n=1;n<=8;n++)
    xr[n-1] = SQ2 * sinf((float)n*PIf*dd)*invd*envv*mask;
  int sp_s = species[senders[e]], sp_r = species[receivers[e]];
  const float* es_ = emb + (size_t)sp_s*32;
  const float* er_ = emb + (size_t)sp_r*32;
#pragma unroll 8
  for (int k=0;k<32;k++){ xr[8+k] = es_[k]*mask; xr[40+k] = er_[k]*mask; }
  float x2=x*x, y2=y*y, z2=z*z;
  const float s3=1.7320508075688772f, s15=3.872983346207417f, s5=2.23606797749979f;
  const float s358=2.0916500663351889f, s105=10.246950765959598f;
  const float s218=1.6201851746019651f, s7=2.6457513110645907f;
  float* Yr = Yb + ((size_t)e<<4);
  Yr[0]=1.f;           Yr[1]=s3*y;          Yr[2]=s3*z;           Yr[3]=s3*x;
  Yr[4]=s15*x*y;       Yr[5]=s15*y*z;       Yr[6]=0.5f*s5*(3.f*z2-1.f);
  Yr[7]=s15*x*z;       Yr[8]=0.5f*s15*(x2-y2);
  Yr[9]=s358*y*(3.f*x2-y2);  Yr[10]=s105*x*y*z;  Yr[11]=s218*y*(5.f*z2-1.f);
  Yr[12]=0.5f*s7*(5.f*z2-3.f)*z;  Yr[13]=s218*x*(5.f*z2-1.f);
  Yr[14]=0.5f*s105*(x2-y2)*z;     Yr[15]=s358*x*(x2-y2);
}

// ---- fused sort prep: hist + scan + perm in one launch (R19) ----
__global__ __launch_bounds__(1024) void sortprep_k(const int* __restrict__ senders,
    int* __restrict__ starts, int* __restrict__ perm)
{
  __shared__ int cnt[NNODES];
  __shared__ int csum[64];
  const int tid = threadIdx.x;
  for (int i = tid; i < NNODES; i += 1024) cnt[i] = 0;
  __syncthreads();
  for (int e = tid; e < E_EDGES; e += 1024) atomicAdd(&cnt[senders[e]], 1);
  __syncthreads();
  if (tid < 64) {
    int s = 0;
    for (int i = 0; i < 32; i++) s += cnt[tid*32 + i];
    csum[tid] = s;
  }
  __syncthreads();
  if (tid == 0) {
    int run = 0;
    for (int i = 0; i < 64; i++) { int c = csum[i]; csum[i] = run; run += c; }
  }
  __syncthreads();
  if (tid < 64) {
    int run = csum[tid];
    for (int i = 0; i < 32; i++) { int c = cnt[tid*32 + i]; cnt[tid*32 + i] = run; run += c; }
  }
  __syncthreads();
  for (int i = tid; i < NNODES; i += 1024) starts[i] = cnt[i];
  if (tid == 0) starts[NNODES] = E_EDGES;
  __syncthreads();
  for (int e = tid; e < E_EDGES; e += 1024) {
    int pos = atomicAdd(&cnt[senders[e]], 1);
    perm[pos] = e;
  }
}

// node[n][a*16+m] = sum_{e: senders[e]==n} w[e][m]*Y[e][a]; block per node.
__global__ __launch_bounds__(256) void nodesum_k(const float* __restrict__ w,
    const float* __restrict__ Y, const int* __restrict__ perm,
    const int* __restrict__ starts, float* __restrict__ node)
{
  __shared__ float buf[8*32];
  const int n = blockIdx.x;
  const int tid = threadIdx.x;
  const int s0 = starts[n], s1 = starts[n+1];
  const int a = tid >> 4, m = tid & 15;
  float acc = 0.f;
  for (int i = s0; i < s1; i += 8) {
    int nb = s1 - i; if (nb > 8) nb = 8;
    int slot = tid >> 5, comp = tid & 31;
    if (slot < nb) {
      int e = perm[i + slot];
      buf[slot*32 + comp] = (comp < 16) ? w[(e<<4)+comp] : Y[(e<<4)+comp-16];
    }
    __syncthreads();
    for (int q = 0; q < nb; q++)
      acc += buf[q*32 + m] * buf[q*32 + 16 + a];
    __syncthreads();
  }
  node[((size_t)n<<8) + tid] = acc;
}

// l3=0 TP standalone (layer 2); B = Vn fp16
__global__ void tp2_k(const float* __restrict__ node, const unsigned short* __restrict__ Vn,
    const int* __restrict__ senders, const float* __restrict__ varepsp,
    const int* __restrict__ pmeta, const int* __restrict__ entIJ,
    const float* __restrict__ entVal, unsigned short* __restrict__ tp0)
{
  const int gid = blockIdx.x*256 + threadIdx.x;
  const int e = gid >> 6, c = gid & 63;
  const int p = c >> 4, m = c & 15;
  float ve = varepsp[0];
  float eps = rsqrtf(1.f + ve*ve);
  int s = senders[e];
  const float* Am = &node[((size_t)s<<8)];
  const unsigned short* Bm = &Vn[((size_t)e<<8)];
  int es = pmeta[p*4+1], ec = pmeta[p*4+2];
  float acc = 0.f;
  for (int t=0;t<ec;t++){
    int ij = entIJ[es+t];
    acc += entVal[es+t] * Am[((ij&255)<<4) + m] * h2f(Bm[(((ij>>8)&255)<<4) + m]);
  }
  tp0[((size_t)e<<6) + pmeta[p*4+0] + m] = f2h(acc * eps);
}

// ============================ host launcher ============================

extern "C" void kernel_launch(void* const* d_in, const int* in_sizes, int n_in,
                              void* d_out, int out_size, void* d_ws, size_t ws_size,
                              hipStream_t stream)
{
  const float* vectors = (const float*)d_in[0];
  const float* vareps  = (const float*)d_in[1];
  const float* alpha   = (const float*)d_in[2];
  const float* emb     = (const float*)d_in[3];
  const float* W_tb1   = (const float*)d_in[4];
  const float* W_tb2   = (const float*)d_in[5];
  const float* W_tb3   = (const float*)d_in[6];
  const float* W_tb4   = (const float*)d_in[7];
  const float* W_w0    = (const float*)d_in[8];
  const float* W_w1    = (const float*)d_in[9];
  const float* W_l11   = (const float*)d_in[10];
  const float* W_l12   = (const float*)d_in[11];
  const float* W_l13   = (const float*)d_in[12];
  const float* W_v1    = (const float*)d_in[13];
  const float* W_v2    = (const float*)d_in[14];
  const float* W_v3    = (const float*)d_in[15];
  const float* W_w2    = (const float*)d_in[16];
  const float* W_l21   = (const float*)d_in[17];
  const float* W_l22   = (const float*)d_in[18];
  const float* W_l23   = (const float*)d_in[19];
  const float* W_h     = (const float*)d_in[20];
  const float* W_out   = (const float*)d_in[21];
  const int* senders   = (const int*)d_in[22];
  const int* receivers = (const int*)d_in[23];
  const int* species   = (const int*)d_in[24];

  static cgt::Tables tb;
  cgt::build(tb);
  const int Kdim = tb.npairs * 16;

  char* ws = (char*)d_ws;
  size_t off = 0;
  auto alloc = [&](size_t bytes)->void*{
    void* p = ws + off; off += (bytes + 255) & ~(size_t)255; return p;
  };
  float* t_val = (float*)alloc(sizeof(tb.val));
  int*   t_ij  = (int*)  alloc(sizeof(tb.ij));
  int*   t_pm  = (int*)  alloc(sizeof(tb.pmeta));
  float* t_td  = (float*)alloc(sizeof(tb.TD));
  int*   t_pr  = (int*)  alloc(sizeof(tb.pairs));
  int*   t_oc  = (int*)  alloc(sizeof(tb.sl_origc));
  float* envb  = (float*)alloc((size_t)E_EDGES*4);
  float* Yb    = (float*)alloc((size_t)E_EDGES*16*4);
  float* xb    = (float*)alloc((size_t)E_EDGES*256*4);
  float* Vb    = (float*)alloc((size_t)E_EDGES*256*4);
  float* bufA  = (float*)alloc((size_t)E_EDGES*72*4);
  float* wb    = (float*)alloc((size_t)E_EDGES*16*4);
  float* tp0b  = (float*)alloc((size_t)E_EDGES*64*4);
  float* nodeb = (float*)alloc((size_t)NNODES*256*4);
  int* startsb = (int*)alloc((NNODES+1)*4);
  int* permb   = (int*)alloc(E_EDGES*4);
  unsigned short* Gt = (unsigned short*)alloc((size_t)256*Kdim*2);
  unsigned short* Wt_tb1 = (unsigned short*)alloc(32*72*2);
  unsigned short* Wt_tb2 = (unsigned short*)alloc(64*32*2);
  unsigned short* Wt_tb3 = (unsigned short*)alloc(128*64*2);
  unsigned short* Wt_tb4 = (unsigned short*)alloc(256*128*2);
  unsigned short* Wt_w01 = (unsigned short*)alloc(32*256*2);
  unsigned short* Wt_w2  = (unsigned short*)alloc(16*256*2);
  unsigned short* Wt_l11 = (unsigned short*)alloc(320*256*2);
  unsigned short* Wt_l12 = (unsigned short*)alloc(256*256*2);
  unsigned short* Wt_l13 = (unsigned short*)alloc(256*256*2);
  unsigned short* Wt_l21 = (unsigned short*)alloc(320*256*2);
  unsigned short* Wt_l22 = (unsigned short*)alloc(256*256*2);
  unsigned short* Wt_l23 = (unsigned short*)alloc(256*256*2);
  if (off > ws_size) {
    fprintf(stderr, "[allegro] workspace too small: need %zu, have %zu\n", off, ws_size);
    return;
  }
  unsigned short* xb16 = (unsigned short*)xb;
  unsigned short* tp016 = (unsigned short*)tp0b;
  unsigned short* V16 = (unsigned short*)Vb;

  hipMemcpyAsync(t_val, tb.val,     sizeof(tb.val),     hipMemcpyHostToDevice, stream);
  hipMemcpyAsync(t_ij,  tb.ij,      sizeof(tb.ij),      hipMemcpyHostToDevice, stream);
  hipMemcpyAsync(t_pm,  tb.pmeta,   sizeof(tb.pmeta),   hipMemcpyHostToDevice, stream);
  hipMemcpyAsync(t_td,  tb.TD,      sizeof(tb.TD),      hipMemcpyHostToDevice, stream);
  hipMemcpyAsync(t_pr,  tb.pairs,   sizeof(tb.pairs),   hipMemcpyHostToDevice, stream);
  hipMemcpyAsync(t_oc,  tb.sl_origc,sizeof(tb.sl_origc),hipMemcpyHostToDevice, stream);

  const int s1b = tb.l3np[0];
  const int s1e = s1b + tb.l3np[1];
  const int s2e = s1e + tb.l3np[2];
  const int s3e = s2e + tb.l3np[3];

  {
    dim3 g((Kdim + 255)/256, 256);
    gbuild_k<<<g, 256, 0, stream>>>(t_td, W_v1, W_v2, W_v3, t_oc, Gt, Kdim,
                                    tb.npairs, s1b, s1e, s2e, s3e);
  }
  {
    WPack p;
    p.d[0] = { W_tb1, Wt_tb1,  72, 5 };
    p.d[1] = { W_tb2, Wt_tb2,  32, 6 };
    p.d[2] = { W_tb3, Wt_tb3,  64, 7 };
    p.d[3] = { W_tb4, Wt_tb4, 128, 8 };
    dim3 g(128, 4);
    wcvt_k<<<g, 256, 0, stream>>>(p);
  }
  {
    WPackT p;
    p.d[0] = { W_l11, Wt_l11, 320, 8 };
    p.d[1] = { W_l12, Wt_l12, 256, 8 };
    p.d[2] = { W_l13, Wt_l13, 256, 8 };
    p.d[3] = { W_l21, Wt_l21, 320, 8 };
    p.d[4] = { W_l22, Wt_l22, 256, 8 };
    p.d[5] = { W_l23, Wt_l23, 256, 8 };
    p.d[6] = { W_w2,  Wt_w2,  256, 4 };
    dim3 g(320, 7);
    wcvt_tile_k<<<g, 256, 0, stream>>>(p);
  }
  wcvt01_k<<<32, 256, 0, stream>>>(W_w0, W_w1, Wt_w01);
  sortprep_k<<<1, 1024, 0, stream>>>(senders, startsb, permb);

  // 1. edge features + Y + env  (x72 -> bufA fp32)
  edge_init_k<<<E_EDGES/256, 256, 0, stream>>>(vectors, senders, receivers, species,
                                               emb, envb, Yb, bufA);
  // 2+3. fused two-body MLP + w0/w1 + V init
  tb_fused_k<<<E_EDGES/64, 256, 0, stream>>>(bufA, Wt_tb1, Wt_tb2, Wt_tb3, Wt_tb4,
                                             Wt_w01, Yb, envb, xb16, V16, wb);

  // ---- layer 1 ----
  nodesum_k<<<NNODES, 256, 0, stream>>>(wb, Yb, permb, startsb, nodeb);
  vn_k<<<E_EDGES/VN_E, 512, 0, stream>>>(nodeb, V16, senders, vareps, t_pr, Gt,
                                         V16, Kdim, t_pm, t_ij, t_val, tp016);
  mlp3_k<0><<<E_EDGES/128, 512, 0, stream>>>(xb16, tp016, Wt_l11, Wt_l12, Wt_l13,
                                             xb16, envb, alpha, Wt_w2, wb,
                                             nullptr, nullptr, nullptr);

  // ---- layer 2 (lmax_out = 0): w2 already in wb from mlp3<0> ----
  nodesum_k<<<NNODES, 256, 0, stream>>>(wb, Yb, permb, startsb, nodeb);
  tp2_k<<<E_EDGES*64/256, 256, 0, stream>>>(nodeb, V16, senders, vareps, t_pm, t_ij,
                                            t_val, tp016);
  mlp3_k<1><<<E_EDGES/128, 512, 0, stream>>>(xb16, tp016, Wt_l21, Wt_l22, Wt_l23,
                                             nullptr, envb, alpha, nullptr, nullptr,
                                             W_h, W_out, (float*)d_out);
}

// Round 20
// 401.355 us; speedup vs baseline: 1.0027x; 1.0027x over previous
//
#include <hip/hip_runtime.h>
#include <cmath>
#include <complex>
#include <cstdio>
#include <cstring>
#include <algorithm>

#define E_EDGES 32768
#define NNODES  2048
#define VN_E    128

// ============================ host-side CG tables ============================
namespace cgt {

static double fct(int n){
  static const double f[13] = {1.,1.,2.,6.,24.,120.,720.,5040.,40320.,362880.,
                               3628800.,39916800.,479001600.};
  return f[n];
}

static double cg(int j1,int m1,int j2,int m2,int j3,int m3){
  if (m1+m2 != m3) return 0.0;
  double pre = std::sqrt((2*j3+1)*fct(j1+j2-j3)*fct(j1-j2+j3)*fct(-j1+j2+j3)/fct(j1+j2+j3+1));
  pre *= std::sqrt(fct(j3+m3)*fct(j3-m3)*fct(j1-m1)*fct(j1+m1)*fct(j2-m2)*fct(j2+m2));
  int kmin = 0;
  if (j2-j3-m1 > kmin) kmin = j2-j3-m1;
  if (j1-j3+m2 > kmin) kmin = j1-j3+m2;
  int kmax = j1+j2-j3;
  if (j1-m1 < kmax) kmax = j1-m1;
  if (j2+m2 < kmax) kmax = j2+m2;
  double s = 0.0;
  for (int k=kmin;k<=kmax;k++){
    double d = fct(k)*fct(j1+j2-j3-k)*fct(j1-m1-k)*fct(j2+m2-k)*fct(j3-j2+m1+k)*fct(j3-j1-m2+k);
    s += ((k&1)? -1.0:1.0)/d;
  }
  return pre*s;
}

typedef std::complex<double> cd;

static void umat(int l, cd U[7][7]){
  for (int a=0;a<7;a++) for (int b=0;b<7;b++) U[a][b]=cd(0,0);
  U[l][l] = cd(1,0);
  double s2 = 1.0/std::sqrt(2.0);
  for (int m=1;m<=l;m++){
    double sg = (m&1)? -1.0 : 1.0;
    U[l+m][l-m] = cd(s2,0);
    U[l+m][l+m] = cd(sg*s2,0);
    U[l-m][l-m] = cd(0, s2);
    U[l-m][l+m] = cd(0, -sg*s2);
  }
}

static bool realCoupling(int l1,int l2,int l3, double T[7][7][7]){
  cd U1[7][7],U2[7][7],U3[7][7];
  umat(l1,U1); umat(l2,U2); umat(l3,U3);
  int n1=2*l1+1, n2=2*l2+1, n3=2*l3+1;
  double Cg[7][7][7];
  for (int m=0;m<n1;m++) for(int n=0;n<n2;n++) for(int k=0;k<n3;k++)
    Cg[m][n][k] = cg(l1,m-l1,l2,n-l2,l3,k-l3);
  double Tr[7][7][7], Ti[7][7][7];
  double nr=0, ni=0;
  for (int a=0;a<n1;a++) for(int b=0;b<n2;b++) for(int c=0;c<n3;c++){
    cd s(0,0);
    for (int m=0;m<n1;m++){
      if (U1[a][m]==cd(0,0)) continue;
      for (int n=0;n<n2;n++){
        if (U2[b][n]==cd(0,0)) continue;
        for (int k=0;k<n3;k++){
          double cgv = Cg[m][n][k];
          if (cgv==0.0) continue;
          s += U1[a][m]*U2[b][n]*std::conj(U3[c][k])*cgv;
        }
      }
    }
    Tr[a][b][c]=s.real(); Ti[a][b][c]=s.imag();
    nr += s.real()*s.real(); ni += s.imag()*s.imag();
  }
  bool useR = (nr >= ni);
  double nn = std::sqrt(useR? nr : ni);
  if (nn < 1e-8) return false;
  for (int a=0;a<n1;a++)for(int b=0;b<n2;b++)for(int c=0;c<n3;c++)
    T[a][b][c] = (useR? Tr[a][b][c] : Ti[a][b][c])/nn;
  return true;
}

struct Tables {
  float val[4096];
  int   ij[4096];
  int   pmeta[40*4];
  int   ccnt[40*8];
  int   l3base[4];
  int   l3np[4];
  int   npaths;
  int   nent;
  int   tptot;
  int   pairs[256];
  float TD[256*30*8];
  int   sl_origc[40];
  int   npairs;
};

struct PathTmp {
  int l1,l2,l3, tpoff, kd;
  int ec;
  double T[7][7][7];
};

static void build(Tables& tb){
  static PathTmp paths[40];
  int np = 0, tpoff = 0;
  int l3start[5];
  for (int l3=0;l3<=3;l3++){
    tb.l3base[l3] = tpoff;
    l3start[l3] = np;
    int kd = 2*l3+1;
    for (int l1=0;l1<=3;l1++) for (int l2=0;l2<=3;l2++){
      int lo = (l1>l2)? l1-l2 : l2-l1;
      int hi = std::min(l1+l2,3);
      if (l3 < lo || l3 > hi) continue;
      PathTmp& pt = paths[np];
      if (!realCoupling(l1,l2,l3,pt.T)) continue;
      pt.l1=l1; pt.l2=l2; pt.l3=l3; pt.kd=kd; pt.tpoff=tpoff;
      double scale = std::sqrt((double)kd);
      int cnt = 0;
      for (int a=0;a<2*l1+1;a++)for(int b=0;b<2*l2+1;b++)for(int c=0;c<kd;c++)
        if (std::fabs(pt.T[a][b][c]*scale) > 1e-7) cnt++;
      pt.ec = cnt;
      tpoff += 16*kd;
      np++;
    }
  }
  l3start[4] = np;
  for (int l3=0;l3<=3;l3++) tb.l3np[l3] = l3start[l3+1]-l3start[l3];
  static int order[40];
  for (int i=0;i<np;i++) order[i]=i;
  for (int l3=0;l3<=3;l3++)
    std::sort(order+l3start[l3], order+l3start[l3+1],
              [&](int a,int b){ return paths[a].ec > paths[b].ec; });
  std::memset(tb.TD, 0, sizeof(tb.TD));
  std::memset(tb.pairs, 0, sizeof(tb.pairs));
  static int pmap[16][16];
  for (int i=0;i<16;i++) for (int j=0;j<16;j++) pmap[i][j] = -1;
  int npr = 0;
  int ep = 0;
  for (int slot=0; slot<np; slot++){
    const PathTmp& pt = paths[order[slot]];
    double scale = std::sqrt((double)pt.kd);
    int s1 = pt.l1*pt.l1, s2 = pt.l2*pt.l2;
    tb.pmeta[slot*4+0] = pt.tpoff;
    tb.pmeta[slot*4+1] = ep;
    tb.sl_origc[slot] = ((pt.tpoff - tb.l3base[pt.l3]) / (16*pt.kd)) * 16;
    int tot = 0;
    for (int c=0;c<pt.kd;c++){
      int cnt = 0;
      for (int a=0;a<2*pt.l1+1;a++)for(int b=0;b<2*pt.l2+1;b++){
        double v = pt.T[a][b][c]*scale;
        if (std::fabs(v) > 1e-7){
          tb.val[ep] = (float)v;
          tb.ij[ep]  = (s1+a) | ((s2+b)<<8);
          ep++; cnt++;
          if (pt.l3 >= 1){
            int aa = s1+a, bb = s2+b;
            int pi = pmap[aa][bb];
            if (pi < 0){ pi = npr; pmap[aa][bb] = pi;
                         tb.pairs[npr] = aa | (bb<<8); npr++; }
            tb.TD[(pi*30 + (slot-4))*8 + c] = (float)v;
          }
        }
      }
      tb.ccnt[slot*8+c] = cnt;
      tot += cnt;
    }
    for (int c=pt.kd;c<8;c++) tb.ccnt[slot*8+c]=0;
    tb.pmeta[slot*4+2] = tot;
    tb.pmeta[slot*4+3] = pt.kd;
  }
  if (npr & 1){ tb.pairs[npr] = 0; npr++; }
  tb.npairs = npr;
  tb.npaths = np; tb.nent = ep; tb.tptot = tpoff;
}

} // namespace cgt

// ============================ device kernels ============================
// LAYOUT: node/V/Vn rows are [a][m]. MFMA-path activations fp16 in HBM.
// Latent-MLP weights pre-tiled [(k/32)*N + n][32] (fragment layout, like Gtt).

typedef _Float16 half8 __attribute__((ext_vector_type(8)));
typedef __attribute__((ext_vector_type(4))) float f32x4;

__device__ inline unsigned short f2h(float f){
  union { _Float16 h; unsigned short u; } x;
  x.h = (_Float16)f;
  return x.u;
}
__device__ inline float h2f(unsigned short u){
  union { _Float16 h; unsigned short u; } x; x.u = u;
  return (float)x.h;
}

__device__ inline int swz(int row, int kh){
  int b = row*64 + kh*2;
  return b ^ (((row >> 1) & 3) << 4);
}

__device__ inline float silu(float v){ return v/(1.f+__expf(-v)); }

#define MFMA16 __builtin_amdgcn_mfma_f32_16x16x32_f16

// ---- fused two-body chain: x72 ->32->64->128->256, + [w0|w1], + V ----
__global__ __launch_bounds__(256) void tb_fused_k(
    const float* __restrict__ X72, const unsigned short* __restrict__ Wt1,
    const unsigned short* __restrict__ Wt2, const unsigned short* __restrict__ Wt3,
    const unsigned short* __restrict__ Wt4, const unsigned short* __restrict__ Wt01,
    const float* __restrict__ Yb, const float* __restrict__ envb,
    unsigned short* __restrict__ Xout, unsigned short* __restrict__ V,
    float* __restrict__ wb)
{
  __shared__ unsigned short AsB[64*32];
  __shared__ unsigned short BsB[256*32];
  __shared__ unsigned short HsA[64*264];
  __shared__ unsigned short HsB[64*264];
  __shared__ float w0s[64*16];
  const int tid  = threadIdx.x;
  const int wave = tid >> 6, lane = tid & 63;
  const int bm = blockIdx.x*64;
  const int mrow = wave*16;
  const int fr = lane & 15, fk = (lane >> 4) * 8;
  const int r4 = (lane >> 4) << 2;
  const int sra = tid >> 2, ska = (tid & 3) * 8;
  const int srb = tid >> 1, skb = (tid & 1) * 16;

  // ---- stage 1: h = silu(x72 @ W1 / sqrt(72)), N=32, K=72 (pad 96) ----
  {
    f32x4 acc[2] = {};
    for (int k0 = 0; k0 < 96; k0 += 32) {
      {
        unsigned short u[8];
        int rowg = bm + sra;
#pragma unroll
        for (int q = 0; q < 8; q++) {
          int k = k0 + ska + q;
          u[q] = (k < 72) ? f2h(X72[(size_t)rowg*72 + k]) : (unsigned short)0;
        }
        *(ushort4*)((char*)AsB + swz(sra, ska))     = *(ushort4*)&u[0];
        *(ushort4*)((char*)AsB + swz(sra, ska + 4)) = *(ushort4*)&u[4];
      }
      if (tid < 64) {
        int n = tid >> 1, kb = (tid & 1) * 16;
        unsigned short u[16];
#pragma unroll
        for (int q = 0; q < 16; q++) {
          int k = k0 + kb + q;
          u[q] = (k < 72) ? Wt1[n*72 + k] : (unsigned short)0;
        }
        *(uint4*)((char*)BsB + swz(n, kb))     = *(uint4*)&u[0];
        *(uint4*)((char*)BsB + swz(n, kb + 8)) = *(uint4*)&u[8];
      }
      __syncthreads();
      half8 af = *(half8*)((char*)AsB + swz(mrow + fr, fk));
      half8 b0 = *(half8*)((char*)BsB + swz(fr, fk));
      half8 b1 = *(half8*)((char*)BsB + swz(16 + fr, fk));
      acc[0] = MFMA16(af, b0, acc[0], 0, 0, 0);
      acc[1] = MFMA16(af, b1, acc[1], 0, 0, 0);
      __syncthreads();
    }
    const float rs = 0.11785113019775793f;
#pragma unroll
    for (int j = 0; j < 2; j++)
#pragma unroll
      for (int r = 0; r < 4; r++) {
        int row = mrow + r4 + r;
        HsA[row*264 + j*16 + fr] = f2h(silu(acc[j][r]*rs));
      }
    __syncthreads();
  }

  // ---- stage 2: h = silu(h @ W2 / sqrt(32)), N=64, K=32 ----
  {
    f32x4 acc[4] = {};
    if (tid < 128) {
      int n = tid >> 1, kb = (tid & 1) * 16;
      const unsigned short* s = Wt2 + n*32 + kb;
      uint4 u0 = *(const uint4*)s;
      uint4 u1 = *(const uint4*)(s + 8);
      *(uint4*)((char*)BsB + swz(n, kb))     = u0;
      *(uint4*)((char*)BsB + swz(n, kb + 8)) = u1;
    }
    __syncthreads();
    half8 af = *(half8*)(HsA + (mrow + fr)*264 + fk);
#pragma unroll
    for (int j = 0; j < 4; j++) {
      half8 bf = *(half8*)((char*)BsB + swz(j*16 + fr, fk));
      acc[j] = MFMA16(af, bf, acc[j], 0, 0, 0);
    }
    __syncthreads();
    const float rs = 0.17677669529663687f;
#pragma unroll
    for (int j = 0; j < 4; j++)
#pragma unroll
      for (int r = 0; r < 4; r++) {
        int row = mrow + r4 + r;
        HsB[row*264 + j*16 + fr] = f2h(silu(acc[j][r]*rs));
      }
    __syncthreads();
  }

  // ---- stage 3: h = silu(h @ W3 / 8), N=128, K=64 ----
  {
    f32x4 acc[8] = {};
    for (int k0 = 0; k0 < 64; k0 += 32) {
      {
        int n = srb, kb = skb;
        const unsigned short* s = Wt3 + n*64 + k0 + kb;
        uint4 u0 = *(const uint4*)s;
        uint4 u1 = *(const uint4*)(s + 8);
        *(uint4*)((char*)BsB + swz(n, kb))     = u0;
        *(uint4*)((char*)BsB + swz(n, kb + 8)) = u1;
      }
      __syncthreads();
      half8 af = *(half8*)(HsB + (mrow + fr)*264 + k0 + fk);
#pragma unroll
      for (int j = 0; j < 8; j++) {
        half8 bf = *(half8*)((char*)BsB + swz(j*16 + fr, fk));
        acc[j] = MFMA16(af, bf, acc[j], 0, 0, 0);
      }
      __syncthreads();
    }
    const float rs = 0.125f;
#pragma unroll
    for (int j = 0; j < 8; j++)
#pragma unroll
      for (int r = 0; r < 4; r++) {
        int row = mrow + r4 + r;
        HsA[row*264 + j*16 + fr] = f2h(silu(acc[j][r]*rs));
      }
    __syncthreads();
  }

  // ---- stage 4: x = env * (h @ W4 / sqrt(128)), N=256, K=128 ----
  {
    f32x4 acc[16] = {};
    for (int k0 = 0; k0 < 128; k0 += 32) {
#pragma unroll
      for (int h = 0; h < 2; h++) {
        int n = h*128 + srb;
        const unsigned short* s = Wt4 + (size_t)n*128 + k0 + skb;
        uint4 u0 = *(const uint4*)s;
        uint4 u1 = *(const uint4*)(s + 8);
        *(uint4*)((char*)BsB + swz(n, skb))     = u0;
        *(uint4*)((char*)BsB + swz(n, skb + 8)) = u1;
      }
      __syncthreads();
      half8 af = *(half8*)(HsA + (mrow + fr)*264 + k0 + fk);
#pragma unroll
      for (int j = 0; j < 16; j++) {
        half8 bf = *(half8*)((char*)BsB + swz(j*16 + fr, fk));
        acc[j] = MFMA16(af, bf, acc[j], 0, 0, 0);
      }
      __syncthreads();
    }
    const float rs = 0.08838834764831845f;
#pragma unroll
    for (int j = 0; j < 16; j++)
#pragma unroll
      for (int r = 0; r < 4; r++) {
        int row = mrow + r4 + r;
        float v = acc[j][r]*rs*envb[bm + row];
        unsigned short hv = f2h(v);
        HsB[row*264 + j*16 + fr] = hv;
        Xout[((size_t)(bm + row))*256 + j*16 + fr] = hv;
      }
    __syncthreads();
  }

  // ---- stage 5: [w0|w1] = x @ [W0|W1] / 16, N=32, K=256 ----
  {
    f32x4 acc[2] = {};
    for (int k0 = 0; k0 < 256; k0 += 32) {
      if (tid < 64) {
        int n = tid >> 1, kb = (tid & 1) * 16;
        const unsigned short* s = Wt01 + (size_t)n*256 + k0 + kb;
        uint4 u0 = *(const uint4*)s;
        uint4 u1 = *(const uint4*)(s + 8);
        *(uint4*)((char*)BsB + swz(n, kb))     = u0;
        *(uint4*)((char*)BsB + swz(n, kb + 8)) = u1;
      }
      __syncthreads();
      half8 af = *(half8*)(HsB + (mrow + fr)*264 + k0 + fk);
      half8 b0 = *(half8*)((char*)BsB + swz(fr, fk));
      half8 b1 = *(half8*)((char*)BsB + swz(16 + fr, fk));
      acc[0] = MFMA16(af, b0, acc[0], 0, 0, 0);
      acc[1] = MFMA16(af, b1, acc[1], 0, 0, 0);
      __syncthreads();
    }
#pragma unroll
    for (int r = 0; r < 4; r++) {
      int row = mrow + r4 + r;
      w0s[row*16 + fr] = acc[0][r]*0.0625f;
      wb[((size_t)(bm + row))*16 + fr] = acc[1][r]*0.0625f;
    }
    __syncthreads();
  }

  // ---- V init ----
  for (int i = tid; i < 64*256; i += 256) {
    int e = i >> 8, idx = i & 255;
    V[(((size_t)(bm + e)) << 8) + idx] =
        f2h(w0s[e*16 + (idx & 15)] * Yb[(bm + e)*16 + (idx >> 4)]);
  }
}

// ---- fused 3-layer latent MLP v3 (R19): barrier-free k-loops ----
// B-operands read directly from L2 in fragment-tiled layout (like vn_k's Gtt),
// 1-step register prefetch; A from global (stage 1) or Hs (stages 2-4).
// Barriers only at stage boundaries (6 total vs ~52 in v2).
// MODE 0: writes x_new + w2 -> wb.  MODE 1: in-LDS head -> outE.
template<int MODE>
__global__ __launch_bounds__(512) void mlp3_k(
    const unsigned short* __restrict__ X, const unsigned short* __restrict__ T0,
    const unsigned short* __restrict__ W1t, const unsigned short* __restrict__ W2t,
    const unsigned short* __restrict__ W3t, unsigned short* __restrict__ Out,
    const float* __restrict__ env, const float* __restrict__ alphap,
    const unsigned short* __restrict__ Wtw2, float* __restrict__ wb,
    const float* __restrict__ Wh, const float* __restrict__ Wout,
    float* __restrict__ outE)
{
  __shared__ unsigned short Hs[128*264];    // 67.6 KB
  __shared__ float hcs[256];
  __shared__ float red[512];
  const int tid  = threadIdx.x;
  const int wave = tid >> 6, lane = tid & 63;
  const int bm = blockIdx.x*128;
  const int rowh = (wave >> 2)*64;
  const int wc = (wave & 3)*64;
  const int fr = lane & 15, fk = (lane >> 4) * 8;
  const int r4 = (lane >> 4) << 2;
  if (MODE == 1 && tid < 256) {
    float s = 0.f;
#pragma unroll 16
    for (int j = 0; j < 128; j++) s += Wh[tid*128 + j] * Wout[j];
    hcs[tid] = s;
  }
  f32x4 acc[4][4] = {};

  // ---- stage 1: h1 = silu([x|tp0] @ W1 / sqrt(320)), 10 steps, no barriers ----
  {
    const unsigned short* bp = W1t + ((size_t)(wc + fr))*32 + fk;
    // A-frag loader: row = bm+rowh+i*16+fr, k = k0+fk
    #define LDA1(i,k0) (*((const half8*)(((k0)+fk < 256) \
        ? X  + (size_t)(bm + rowh + (i)*16 + fr)*256 + (k0) + fk \
        : T0 + (size_t)(bm + rowh + (i)*16 + fr)*64  + (k0) + fk - 256)))
    half8 a0 = LDA1(0,0), a1 = LDA1(1,0), a2 = LDA1(2,0), a3 = LDA1(3,0);
    half8 b0 = *(const half8*)(bp);
    half8 b1 = *(const half8*)(bp + 512);
    half8 b2 = *(const half8*)(bp + 1024);
    half8 b3 = *(const half8*)(bp + 1536);
    for (int sl = 0; sl < 10; sl++) {
      half8 na0, na1, na2, na3, nb0, nb1, nb2, nb3;
      if (sl + 1 < 10) {
        int k0n = (sl + 1)*32;
        na0 = LDA1(0,k0n); na1 = LDA1(1,k0n); na2 = LDA1(2,k0n); na3 = LDA1(3,k0n);
        const unsigned short* bn = bp + (size_t)(sl + 1)*8192;
        nb0 = *(const half8*)(bn);
        nb1 = *(const half8*)(bn + 512);
        nb2 = *(const half8*)(bn + 1024);
        nb3 = *(const half8*)(bn + 1536);
      } else { na0=a0; na1=a1; na2=a2; na3=a3; nb0=b0; nb1=b1; nb2=b2; nb3=b3; }
      acc[0][0] = MFMA16(a0, b0, acc[0][0], 0, 0, 0);
      acc[1][0] = MFMA16(a1, b0, acc[1][0], 0, 0, 0);
      acc[2][0] = MFMA16(a2, b0, acc[2][0], 0, 0, 0);
      acc[3][0] = MFMA16(a3, b0, acc[3][0], 0, 0, 0);
      acc[0][1] = MFMA16(a0, b1, acc[0][1], 0, 0, 0);
      acc[1][1] = MFMA16(a1, b1, acc[1][1], 0, 0, 0);
      acc[2][1] = MFMA16(a2, b1, acc[2][1], 0, 0, 0);
      acc[3][1] = MFMA16(a3, b1, acc[3][1], 0, 0, 0);
      acc[0][2] = MFMA16(a0, b2, acc[0][2], 0, 0, 0);
      acc[1][2] = MFMA16(a1, b2, acc[1][2], 0, 0, 0);
      acc[2][2] = MFMA16(a2, b2, acc[2][2], 0, 0, 0);
      acc[3][2] = MFMA16(a3, b2, acc[3][2], 0, 0, 0);
      acc[0][3] = MFMA16(a0, b3, acc[0][3], 0, 0, 0);
      acc[1][3] = MFMA16(a1, b3, acc[1][3], 0, 0, 0);
      acc[2][3] = MFMA16(a2, b3, acc[2][3], 0, 0, 0);
      acc[3][3] = MFMA16(a3, b3, acc[3][3], 0, 0, 0);
      a0=na0; a1=na1; a2=na2; a3=na3; b0=nb0; b1=nb1; b2=nb2; b3=nb3;
    }
    #undef LDA1
  }
  const float rs320 = 0.055901699437494740f;
#pragma unroll
  for (int i = 0; i < 4; i++)
#pragma unroll
    for (int r = 0; r < 4; r++) {
      int row = rowh + i*16 + r4 + r;
#pragma unroll
      for (int j = 0; j < 4; j++) {
        Hs[row*264 + wc + j*16 + fr] = f2h(silu(acc[i][j][r]*rs320));
        acc[i][j][r] = 0.f;
      }
    }
  __syncthreads();

  // ---- stage 2: h2 = silu(h1 @ W2 / 16), 8 steps, no barriers ----
  {
    const unsigned short* bp = W2t + ((size_t)(wc + fr))*32 + fk;
    half8 b0 = *(const half8*)(bp);
    half8 b1 = *(const half8*)(bp + 512);
    half8 b2 = *(const half8*)(bp + 1024);
    half8 b3 = *(const half8*)(bp + 1536);
    for (int sl = 0; sl < 8; sl++) {
      half8 nb0, nb1, nb2, nb3;
      if (sl + 1 < 8) {
        const unsigned short* bn = bp + (size_t)(sl + 1)*8192;
        nb0 = *(const half8*)(bn);
        nb1 = *(const half8*)(bn + 512);
        nb2 = *(const half8*)(bn + 1024);
        nb3 = *(const half8*)(bn + 1536);
      } else { nb0=b0; nb1=b1; nb2=b2; nb3=b3; }
      int k0 = sl*32;
      half8 a0 = *(half8*)(Hs + (rowh +  0 + fr)*264 + k0 + fk);
      half8 a1 = *(half8*)(Hs + (rowh + 16 + fr)*264 + k0 + fk);
      half8 a2 = *(half8*)(Hs + (rowh + 32 + fr)*264 + k0 + fk);
      half8 a3 = *(half8*)(Hs + (rowh + 48 + fr)*264 + k0 + fk);
      acc[0][0] = MFMA16(a0, b0, acc[0][0], 0, 0, 0);
      acc[1][0] = MFMA16(a1, b0, acc[1][0], 0, 0, 0);
      acc[2][0] = MFMA16(a2, b0, acc[2][0], 0, 0, 0);
      acc[3][0] = MFMA16(a3, b0, acc[3][0], 0, 0, 0);
      acc[0][1] = MFMA16(a0, b1, acc[0][1], 0, 0, 0);
      acc[1][1] = MFMA16(a1, b1, acc[1][1], 0, 0, 0);
      acc[2][1] = MFMA16(a2, b1, acc[2][1], 0, 0, 0);
      acc[3][1] = MFMA16(a3, b1, acc[3][1], 0, 0, 0);
      acc[0][2] = MFMA16(a0, b2, acc[0][2], 0, 0, 0);
      acc[1][2] = MFMA16(a1, b2, acc[1][2], 0, 0, 0);
      acc[2][2] = MFMA16(a2, b2, acc[2][2], 0, 0, 0);
      acc[3][2] = MFMA16(a3, b2, acc[3][2], 0, 0, 0);
      acc[0][3] = MFMA16(a0, b3, acc[0][3], 0, 0, 0);
      acc[1][3] = MFMA16(a1, b3, acc[1][3], 0, 0, 0);
      acc[2][3] = MFMA16(a2, b3, acc[2][3], 0, 0, 0);
      acc[3][3] = MFMA16(a3, b3, acc[3][3], 0, 0, 0);
      b0=nb0; b1=nb1; b2=nb2; b3=nb3;
    }
  }
  __syncthreads();   // all reads of h1 done before overwrite
#pragma unroll
  for (int i = 0; i < 4; i++)
#pragma unroll
    for (int r = 0; r < 4; r++) {
      int row = rowh + i*16 + r4 + r;
#pragma unroll
      for (int j = 0; j < 4; j++) {
        Hs[row*264 + wc + j*16 + fr] = f2h(silu(acc[i][j][r]*0.0625f));
        acc[i][j][r] = 0.f;
      }
    }
  __syncthreads();

  // ---- stage 3: x_new = resid(env * (h2 @ W3 / 16)), 8 steps, no barriers ----
  {
    const unsigned short* bp = W3t + ((size_t)(wc + fr))*32 + fk;
    half8 b0 = *(const half8*)(bp);
    half8 b1 = *(const half8*)(bp + 512);
    half8 b2 = *(const half8*)(bp + 1024);
    half8 b3 = *(const half8*)(bp + 1536);
    for (int sl = 0; sl < 8; sl++) {
      half8 nb0, nb1, nb2, nb3;
      if (sl + 1 < 8) {
        const unsigned short* bn = bp + (size_t)(sl + 1)*8192;
        nb0 = *(const half8*)(bn);
        nb1 = *(const half8*)(bn + 512);
        nb2 = *(const half8*)(bn + 1024);
        nb3 = *(const half8*)(bn + 1536);
      } else { nb0=b0; nb1=b1; nb2=b2; nb3=b3; }
      int k0 = sl*32;
      half8 a0 = *(half8*)(Hs + (rowh +  0 + fr)*264 + k0 + fk);
      half8 a1 = *(half8*)(Hs + (rowh + 16 + fr)*264 + k0 + fk);
      half8 a2 = *(half8*)(Hs + (rowh + 32 + fr)*264 + k0 + fk);
      half8 a3 = *(half8*)(Hs + (rowh + 48 + fr)*264 + k0 + fk);
      acc[0][0] = MFMA16(a0, b0, acc[0][0], 0, 0, 0);
      acc[1][0] = MFMA16(a1, b0, acc[1][0], 0, 0, 0);
      acc[2][0] = MFMA16(a2, b0, acc[2][0], 0, 0, 0);
      acc[3][0] = MFMA16(a3, b0, acc[3][0], 0, 0, 0);
      acc[0][1] = MFMA16(a0, b1, acc[0][1], 0, 0, 0);
      acc[1][1] = MFMA16(a1, b1, acc[1][1], 0, 0, 0);
      acc[2][1] = MFMA16(a2, b1, acc[2][1], 0, 0, 0);
      acc[3][1] = MFMA16(a3, b1, acc[3][1], 0, 0, 0);
      acc[0][2] = MFMA16(a0, b2, acc[0][2], 0, 0, 0);
      acc[1][2] = MFMA16(a1, b2, acc[1][2], 0, 0, 0);
      acc[2][2] = MFMA16(a2, b2, acc[2][2], 0, 0, 0);
      acc[3][2] = MFMA16(a3, b2, acc[3][2], 0, 0, 0);
      acc[0][3] = MFMA16(a0, b3, acc[0][3], 0, 0, 0);
      acc[1][3] = MFMA16(a1, b3, acc[1][3], 0, 0, 0);
      acc[2][3] = MFMA16(a2, b3, acc[2][3], 0, 0, 0);
      acc[3][3] = MFMA16(a3, b3, acc[3][3], 0, 0, 0);
      b0=nb0; b1=nb1; b2=nb2; b3=nb3;
    }
  }
  __syncthreads();
  {
    float al = alphap[0];
    float a2 = al*al, inv1a2 = 1.f/(1.f+a2);
#pragma unroll
    for (int i = 0; i < 4; i++)
#pragma unroll
      for (int r = 0; r < 4; r++) {
        int row = rowh + i*16 + r4 + r;
        int grow = bm + row;
        float ev = env[grow];
#pragma unroll
        for (int j = 0; j < 4; j++) {
          int col = wc + j*16 + fr;
          float v = acc[i][j][r]*0.0625f*ev;
          v = (h2f(X[(size_t)grow*256 + col]) + a2*v)*inv1a2;
          unsigned short hv = f2h(v);
          Hs[row*264 + col] = hv;
          if (MODE == 0) Out[(size_t)grow*256 + col] = hv;
        }
      }
  }
  __syncthreads();

  if (MODE == 0) {
    // ---- stage 4: w2 = x_new @ W_w2 / 16 (tiled, N=16), waves wc==0 only ----
    if ((wave & 3) == 0) {
      f32x4 acc2[4] = {};
      const unsigned short* bp = Wtw2 + ((size_t)fr)*32 + fk;
      half8 bf = *(const half8*)(bp);
      for (int sl = 0; sl < 8; sl++) {
        half8 nbf = (sl + 1 < 8) ? *(const half8*)(bp + (size_t)(sl + 1)*512) : bf;
        int k0 = sl*32;
#pragma unroll
        for (int i = 0; i < 4; i++) {
          half8 af = *(half8*)(Hs + (rowh + i*16 + fr)*264 + k0 + fk);
          acc2[i] = MFMA16(af, bf, acc2[i], 0, 0, 0);
        }
        bf = nbf;
      }
#pragma unroll
      for (int i = 0; i < 4; i++)
#pragma unroll
        for (int r = 0; r < 4; r++)
          wb[((size_t)(bm + rowh + i*16 + r4 + r))*16 + fr] = acc2[i][r]*0.0625f;
    }
  } else {
    // ---- final head: out[e] = env * dot(x_new, hc) / (16*sqrt(128)) ----
    int row = tid >> 2, q = tid & 3;
    float p = 0.f;
#pragma unroll 16
    for (int c = q*64; c < q*64 + 64; c++)
      p += h2f(Hs[row*264 + c]) * hcs[c];
    red[tid] = p;
    __syncthreads();
    if (q == 0) {
      float t = red[tid] + red[tid+1] + red[tid+2] + red[tid+3];
      outE[bm + row] = env[bm + row]*t*0.0055242717280199023f;
    }
  }
}

// ---- fused Vn kernel + layer-1 tp0 ----
__global__ __launch_bounds__(512) void vn_k(
    const float* __restrict__ node, const unsigned short* __restrict__ V,
    const int* __restrict__ senders, const float* __restrict__ varepsp,
    const int* __restrict__ pairsG, const unsigned short* __restrict__ Gtt,
    unsigned short* __restrict__ Vn, int Kdim,
    const int* __restrict__ pmeta, const int* __restrict__ entIJ,
    const float* __restrict__ entVal, unsigned short* __restrict__ tp0)
{
  __shared__ unsigned short Ab[VN_E*264];
  __shared__ unsigned short Bb[VN_E*264];
  __shared__ int Ps[256];
  const int tid = threadIdx.x;
  const int e0 = blockIdx.x * VN_E;
  const int wave = tid >> 6, lane = tid & 63;
  float ve = varepsp[0];
  float eps = rsqrtf(1.f + ve*ve);
  if (tid < 256) Ps[tid] = pairsG[tid];
#pragma unroll
  for (int rr = 0; rr < 16; rr++) {
    int row = wave*16 + rr;
    int s = senders[e0 + row];
    float4 fa = *(const float4*)(node + ((size_t)s << 8) + 4*lane);
    uint2 ub = *(const uint2*)(V + (((size_t)(e0 + row)) << 8) + 4*lane);
    unsigned short* ad = Ab + row*264 + 4*lane;
    unsigned short* bd = Bb + row*264 + 4*lane;
    uint2 ua;
    ua.x = (unsigned)f2h(fa.x*eps) | ((unsigned)f2h(fa.y*eps) << 16);
    ua.y = (unsigned)f2h(fa.z*eps) | ((unsigned)f2h(fa.w*eps) << 16);
    *(uint2*)ad = ua;
    *(uint2*)bd = ub;
  }
  __syncthreads();
  for (int o = tid; o < VN_E*64; o += 512) {
    int e = o >> 6, c = o & 63;
    int p = c >> 4, m = c & 15;
    const unsigned short* Ae = Ab + e*264;
    const unsigned short* Be = Bb + e*264;
    int es = pmeta[p*4+1], ec = pmeta[p*4+2];
    float acc = 0.f;
    for (int t = 0; t < ec; t++) {
      int ij = entIJ[es+t];
      acc += entVal[es+t] * h2f(Ae[((ij&255)<<4)+m]) * h2f(Be[(((ij>>8)&255)<<4)+m]);
    }
    tp0[((size_t)(e0+e)<<6) + pmeta[p*4+0] + m] = f2h(acc);
  }
  const int rowb = (wave & 1) * 64;
  const int wc   = (wave >> 1) * 64;
  const int fr = lane & 15, fk = (lane >> 4) * 8;
  const int pairSel = fk >> 4;
  const int moff = fk & 15;
  const int nslab = Kdim >> 5;
  f32x4 acc[4][4] = {};

  const unsigned short* Ar0 = Ab + (rowb + fr)*264;
  const unsigned short* Br0 = Bb + (rowb + fr)*264;
  const unsigned short* Ar1 = Ab + (rowb + 16 + fr)*264;
  const unsigned short* Br1 = Bb + (rowb + 16 + fr)*264;
  const unsigned short* Ar2 = Ab + (rowb + 32 + fr)*264;
  const unsigned short* Br2 = Bb + (rowb + 32 + fr)*264;
  const unsigned short* Ar3 = Ab + (rowb + 48 + fr)*264;
  const unsigned short* Br3 = Bb + (rowb + 48 + fr)*264;

  const unsigned short* gp = Gtt + ((size_t)(wc + fr)) * 32 + fk;
  half8 b0 = *(const half8*)(gp);
  half8 b1 = *(const half8*)(gp + 512);
  half8 b2 = *(const half8*)(gp + 1024);
  half8 b3 = *(const half8*)(gp + 1536);
  half8 c0 = b0, c1 = b1, c2 = b2, c3 = b3;
  if (nslab > 1) {
    const unsigned short* g1 = gp + 8192;
    c0 = *(const half8*)(g1);
    c1 = *(const half8*)(g1 + 512);
    c2 = *(const half8*)(g1 + 1024);
    c3 = *(const half8*)(g1 + 1536);
  }
  int p0 = Ps[pairSel];
  int aoff = ((p0 & 255) << 4) + moff;
  int boff = (((p0 >> 8) & 255) << 4) + moff;
  half8 rA0 = *(const half8*)(Ar0 + aoff);
  half8 rB0 = *(const half8*)(Br0 + boff);
  half8 rA1 = *(const half8*)(Ar1 + aoff);
  half8 rB1 = *(const half8*)(Br1 + boff);
  half8 rA2 = *(const half8*)(Ar2 + aoff);
  half8 rB2 = *(const half8*)(Br2 + boff);
  half8 rA3 = *(const half8*)(Ar3 + aoff);
  half8 rB3 = *(const half8*)(Br3 + boff);

  for (int sl = 0; sl < nslab; sl++) {
    half8 a0 = rA0 * rB0;
    half8 a1 = rA1 * rB1;
    half8 a2 = rA2 * rB2;
    half8 a3 = rA3 * rB3;
    if (sl + 1 < nslab) {
      int pn = Ps[2*(sl + 1) + pairSel];
      int aoffn = ((pn & 255) << 4) + moff;
      int boffn = (((pn >> 8) & 255) << 4) + moff;
      rA0 = *(const half8*)(Ar0 + aoffn);
      rB0 = *(const half8*)(Br0 + boffn);
      rA1 = *(const half8*)(Ar1 + aoffn);
      rB1 = *(const half8*)(Br1 + boffn);
      rA2 = *(const half8*)(Ar2 + aoffn);
      rB2 = *(const half8*)(Br2 + boffn);
      rA3 = *(const half8*)(Ar3 + aoffn);
      rB3 = *(const half8*)(Br3 + boffn);
    }
    half8 d0, d1, d2, d3;
    if (sl + 2 < nslab) {
      const unsigned short* gn = gp + (size_t)(sl + 2) * 8192;
      d0 = *(const half8*)(gn);
      d1 = *(const half8*)(gn + 512);
      d2 = *(const half8*)(gn + 1024);
      d3 = *(const half8*)(gn + 1536);
    } else { d0 = c0; d1 = c1; d2 = c2; d3 = c3; }
    acc[0][0] = MFMA16(a0, b0, acc[0][0], 0, 0, 0);
    acc[1][0] = MFMA16(a1, b0, acc[1][0], 0, 0, 0);
    acc[2][0] = MFMA16(a2, b0, acc[2][0], 0, 0, 0);
    acc[3][0] = MFMA16(a3, b0, acc[3][0], 0, 0, 0);
    acc[0][1] = MFMA16(a0, b1, acc[0][1], 0, 0, 0);
    acc[1][1] = MFMA16(a1, b1, acc[1][1], 0, 0, 0);
    acc[2][1] = MFMA16(a2, b1, acc[2][1], 0, 0, 0);
    acc[3][1] = MFMA16(a3, b1, acc[3][1], 0, 0, 0);
    acc[0][2] = MFMA16(a0, b2, acc[0][2], 0, 0, 0);
    acc[1][2] = MFMA16(a1, b2, acc[1][2], 0, 0, 0);
    acc[2][2] = MFMA16(a2, b2, acc[2][2], 0, 0, 0);
    acc[3][2] = MFMA16(a3, b2, acc[3][2], 0, 0, 0);
    acc[0][3] = MFMA16(a0, b3, acc[0][3], 0, 0, 0);
    acc[1][3] = MFMA16(a1, b3, acc[1][3], 0, 0, 0);
    acc[2][3] = MFMA16(a2, b3, acc[2][3], 0, 0, 0);
    acc[3][3] = MFMA16(a3, b3, acc[3][3], 0, 0, 0);
    b0 = c0; b1 = c1; b2 = c2; b3 = c3;
    c0 = d0; c1 = d1; c2 = d2; c3 = d3;
  }
  const int r4 = (lane >> 4) << 2;
#pragma unroll
  for (int rg = 0; rg < 4; rg++) {
#pragma unroll
    for (int j = 0; j < 4; j++) {
#pragma unroll
      for (int r = 0; r < 4; r++) {
        int row = e0 + rowb + rg*16 + r4 + r;
        int col = wc + j*16 + fr;
        Vn[(size_t)row*256 + col] = f2h(acc[rg][j][r]);
      }
    }
  }
}

// ---- Gtt[slab][col][32] = coupling x Wv (fp16, tiled). col = kabs*16+d ----
__global__ void gbuild_k(const float* __restrict__ TD,
    const float* __restrict__ Wv1, const float* __restrict__ Wv2,
    const float* __restrict__ Wv3, const int* __restrict__ sl_origc,
    unsigned short* __restrict__ Gt, int Kdim, int npairs,
    int s1b, int s1e, int s2e, int s3e)
{
  int k = blockIdx.x*256 + threadIdx.x;
  if (k >= Kdim) return;
  int col = blockIdx.y;
  int pair = k >> 4, m = k & 15;
  int d = col & 15, kabs = col >> 4;
  float acc = 0.f;
  if (kabs > 0 && pair < npairs) {
    const float* Wv; int ss, se, kloc;
    if (kabs < 4)      { Wv = Wv1; ss = s1b; se = s1e; kloc = kabs - 1; }
    else if (kabs < 9) { Wv = Wv2; ss = s1e; se = s2e; kloc = kabs - 4; }
    else               { Wv = Wv3; ss = s2e; se = s3e; kloc = kabs - 9; }
    for (int slot = ss; slot < se; slot++)
      acc += TD[((pair*30) + (slot - 4))*8 + kloc] * Wv[(sl_origc[slot] + m)*16 + d];
    acc *= rsqrtf((float)(16*(se - ss)));
  }
  Gt[((size_t)((k >> 5)*256 + col))*32 + (k & 31)] = f2h(acc);
}

// ---- weight convert + transpose: Wt[n][k] = fp16(W[k][n]) (row-major) ----
struct WDesc { const float* src; unsigned short* dst; int K; int lgN; };
struct WPack { WDesc d[4]; };
__global__ void wcvt_k(WPack p){
  WDesc d = p.d[blockIdx.y];
  int total = d.K << d.lgN;
  int gid = blockIdx.x*256 + threadIdx.x;
  if (gid >= total) return;
  int k = gid >> d.lgN, n = gid & ((1 << d.lgN) - 1);
  d.dst[(size_t)n*d.K + k] = f2h(d.src[gid]);
}

// ---- tiled convert: dst[((k/32)*N + n)*32 + k%32] = fp16(W[k][n]) ----
struct WPackT { WDesc d[7]; };
__global__ void wcvt_tile_k(WPackT p){
  WDesc d = p.d[blockIdx.y];
  int total = d.K << d.lgN;
  int gid = blockIdx.x*256 + threadIdx.x;
  if (gid >= total) return;
  int k = gid >> d.lgN, n = gid & ((1 << d.lgN) - 1);
  d.dst[(((size_t)(k >> 5) << d.lgN) + n)*32 + (k & 31)] = f2h(d.src[gid]);
}

// ---- Wt01[n][k]: n<16 -> W0[k][n]; n>=16 -> W1[k][n-16] ----
__global__ void wcvt01_k(const float* __restrict__ W0, const float* __restrict__ W1,
                         unsigned short* __restrict__ dst){
  int gid = blockIdx.x*256 + threadIdx.x;
  int k = gid >> 5, n = gid & 31;
  float v = (n < 16) ? W0[k*16 + n] : W1[k*16 + (n - 16)];
  dst[(size_t)n*256 + k] = f2h(v);
}

__global__ void edge_init_k(const float* __restrict__ vectors, const int* __restrict__ senders,
    const int* __restrict__ receivers, const int* __restrict__ species,
    const float* __restrict__ emb, float* __restrict__ envb, float* __restrict__ Yb,
    float* __restrict__ x72)
{
  const int e = blockIdx.x*256 + threadIdx.x;
  float vx = vectors[e*3+0], vy = vectors[e*3+1], vz = vectors[e*3+2];
  float d = sqrtf(vx*vx+vy*vy+vz*vz);
  float dd = (d==0.f) ? 1.f : d;
  float invd = 1.f/dd;
  float x = vx*invd, y = vy*invd, z = vz*invd;
  float d2=d*d, d3=d2*d, d6=d3*d3, d7=d6*d, d8=d7*d;
  float envv = (d<1.f) ? (1.f - 28.f*d6 + 48.f*d7 - 21.f*d8) : 0.f;
  envb[e] = envv;
  float mask = (d==0.f)?0.f:1.f;
  const float SQ2 = 1.41421356237309515f;
  const float PIf = 3.14159265358979323846f;
  float* xr = x72 + (size_t)e*72;
#pragma unroll
  for (int n=1;n<=8;n++)
    xr[n-1] = SQ2 * sinf((float)n*PIf*dd)*invd*envv*mask;
  int sp_s = species[senders[e]], sp_r = species[receivers[e]];
  const float* es_ = emb + (size_t)sp_s*32;
  const float* er_ = emb + (size_t)sp_r*32;
#pragma unroll 8
  for (int k=0;k<32;k++){ xr[8+k] = es_[k]*mask; xr[40+k] = er_[k]*mask; }
  float x2=x*x, y2=y*y, z2=z*z;
  const float s3=1.7320508075688772f, s15=3.872983346207417f, s5=2.23606797749979f;
  const float s358=2.0916500663351889f, s105=10.246950765959598f;
  const float s218=1.6201851746019651f, s7=2.6457513110645907f;
  float* Yr = Yb + ((size_t)e<<4);
  Yr[0]=1.f;           Yr[1]=s3*y;          Yr[2]=s3*z;           Yr[3]=s3*x;
  Yr[4]=s15*x*y;       Yr[5]=s15*y*z;       Yr[6]=0.5f*s5*(3.f*z2-1.f);
  Yr[7]=s15*x*z;       Yr[8]=0.5f*s15*(x2-y2);
  Yr[9]=s358*y*(3.f*x2-y2);  Yr[10]=s105*x*y*z;  Yr[11]=s218*y*(5.f*z2-1.f);
  Yr[12]=0.5f*s7*(5.f*z2-3.f)*z;  Yr[13]=s218*x*(5.f*z2-1.f);
  Yr[14]=0.5f*s105*(x2-y2)*z;     Yr[15]=s358*x*(x2-y2);
}

// ---- fused sort prep: hist + scan + perm in one launch (R19) ----
__global__ __launch_bounds__(1024) void sortprep_k(const int* __restrict__ senders,
    int* __restrict__ starts, int* __restrict__ perm)
{
  __shared__ int cnt[NNODES];
  __shared__ int csum[64];
  const int tid = threadIdx.x;
  for (int i = tid; i < NNODES; i += 1024) cnt[i] = 0;
  __syncthreads();
  for (int e = tid; e < E_EDGES; e += 1024) atomicAdd(&cnt[senders[e]], 1);
  __syncthreads();
  if (tid < 64) {
    int s = 0;
    for (int i = 0; i < 32; i++) s += cnt[tid*32 + i];
    csum[tid] = s;
  }
  __syncthreads();
  if (tid == 0) {
    int run = 0;
    for (int i = 0; i < 64; i++) { int c = csum[i]; csum[i] = run; run += c; }
  }
  __syncthreads();
  if (tid < 64) {
    int run = csum[tid];
    for (int i = 0; i < 32; i++) { int c = cnt[tid*32 + i]; cnt[tid*32 + i] = run; run += c; }
  }
  __syncthreads();
  for (int i = tid; i < NNODES; i += 1024) starts[i] = cnt[i];
  if (tid == 0) starts[NNODES] = E_EDGES;
  __syncthreads();
  for (int e = tid; e < E_EDGES; e += 1024) {
    int pos = atomicAdd(&cnt[senders[e]], 1);
    perm[pos] = e;
  }
}

// node[n][a*16+m] = sum_{e: senders[e]==n} w[e][m]*Y[e][a]; block per node.
__global__ __launch_bounds__(256) void nodesum_k(const float* __restrict__ w,
    const float* __restrict__ Y, const int* __restrict__ perm,
    const int* __restrict__ starts, float* __restrict__ node)
{
  __shared__ float buf[8*32];
  const int n = blockIdx.x;
  const int tid = threadIdx.x;
  const int s0 = starts[n], s1 = starts[n+1];
  const int a = tid >> 4, m = tid & 15;
  float acc = 0.f;
  for (int i = s0; i < s1; i += 8) {
    int nb = s1 - i; if (nb > 8) nb = 8;
    int slot = tid >> 5, comp = tid & 31;
    if (slot < nb) {
      int e = perm[i + slot];
      buf[slot*32 + comp] = (comp < 16) ? w[(e<<4)+comp] : Y[(e<<4)+comp-16];
    }
    __syncthreads();
    for (int q = 0; q < nb; q++)
      acc += buf[q*32 + m] * buf[q*32 + 16 + a];
    __syncthreads();
  }
  node[((size_t)n<<8) + tid] = acc;
}

// l3=0 TP standalone (layer 2); B = Vn fp16
__global__ void tp2_k(const float* __restrict__ node, const unsigned short* __restrict__ Vn,
    const int* __restrict__ senders, const float* __restrict__ varepsp,
    const int* __restrict__ pmeta, const int* __restrict__ entIJ,
    const float* __restrict__ entVal, unsigned short* __restrict__ tp0)
{
  const int gid = blockIdx.x*256 + threadIdx.x;
  const int e = gid >> 6, c = gid & 63;
  const int p = c >> 4, m = c & 15;
  float ve = varepsp[0];
  float eps = rsqrtf(1.f + ve*ve);
  int s = senders[e];
  const float* Am = &node[((size_t)s<<8)];
  const unsigned short* Bm = &Vn[((size_t)e<<8)];
  int es = pmeta[p*4+1], ec = pmeta[p*4+2];
  float acc = 0.f;
  for (int t=0;t<ec;t++){
    int ij = entIJ[es+t];
    acc += entVal[es+t] * Am[((ij&255)<<4) + m] * h2f(Bm[(((ij>>8)&255)<<4) + m]);
  }
  tp0[((size_t)e<<6) + pmeta[p*4+0] + m] = f2h(acc * eps);
}

// ============================ host launcher ============================

extern "C" void kernel_launch(void* const* d_in, const int* in_sizes, int n_in,
                              void* d_out, int out_size, void* d_ws, size_t ws_size,
                              hipStream_t stream)
{
  const float* vectors = (const float*)d_in[0];
  const float* vareps  = (const float*)d_in[1];
  const float* alpha   = (const float*)d_in[2];
  const float* emb     = (const float*)d_in[3];
  const float* W_tb1   = (const float*)d_in[4];
  const float* W_tb2   = (const float*)d_in[5];
  const float* W_tb3   = (const float*)d_in[6];
  const float* W_tb4   = (const float*)d_in[7];
  const float* W_w0    = (const float*)d_in[8];
  const float* W_w1    = (const float*)d_in[9];
  const float* W_l11   = (const float*)d_in[10];
  const float* W_l12   = (const float*)d_in[11];
  const float* W_l13   = (const float*)d_in[12];
  const float* W_v1    = (const float*)d_in[13];
  const float* W_v2    = (const float*)d_in[14];
  const float* W_v3    = (const float*)d_in[15];
  const float* W_w2    = (const float*)d_in[16];
  const float* W_l21   = (const float*)d_in[17];
  const float* W_l22   = (const float*)d_in[18];
  const float* W_l23   = (const float*)d_in[19];
  const float* W_h     = (const float*)d_in[20];
  const float* W_out   = (const float*)d_in[21];
  const int* senders   = (const int*)d_in[22];
  const int* receivers = (const int*)d_in[23];
  const int* species   = (const int*)d_in[24];

  static cgt::Tables tb;
  cgt::build(tb);
  const int Kdim = tb.npairs * 16;

  char* ws = (char*)d_ws;
  size_t off = 0;
  auto alloc = [&](size_t bytes)->void*{
    void* p = ws + off; off += (bytes + 255) & ~(size_t)255; return p;
  };
  float* t_val = (float*)alloc(sizeof(tb.val));
  int*   t_ij  = (int*)  alloc(sizeof(tb.ij));
  int*   t_pm  = (int*)  alloc(sizeof(tb.pmeta));
  float* t_td  = (float*)alloc(sizeof(tb.TD));
  int*   t_pr  = (int*)  alloc(sizeof(tb.pairs));
  int*   t_oc  = (int*)  alloc(sizeof(tb.sl_origc));
  float* envb  = (float*)alloc((size_t)E_EDGES*4);
  float* Yb    = (float*)alloc((size_t)E_EDGES*16*4);
  float* xb    = (float*)alloc((size_t)E_EDGES*256*4);
  float* Vb    = (float*)alloc((size_t)E_EDGES*256*4);
  float* bufA  = (float*)alloc((size_t)E_EDGES*72*4);
  float* wb    = (float*)alloc((size_t)E_EDGES*16*4);
  float* tp0b  = (float*)alloc((size_t)E_EDGES*64*4);
  float* nodeb = (float*)alloc((size_t)NNODES*256*4);
  int* startsb = (int*)alloc((NNODES+1)*4);
  int* permb   = (int*)alloc(E_EDGES*4);
  unsigned short* Gt = (unsigned short*)alloc((size_t)256*Kdim*2);
  unsigned short* Wt_tb1 = (unsigned short*)alloc(32*72*2);
  unsigned short* Wt_tb2 = (unsigned short*)alloc(64*32*2);
  unsigned short* Wt_tb3 = (unsigned short*)alloc(128*64*2);
  unsigned short* Wt_tb4 = (unsigned short*)alloc(256*128*2);
  unsigned short* Wt_w01 = (unsigned short*)alloc(32*256*2);
  unsigned short* Wt_w2  = (unsigned short*)alloc(16*256*2);
  unsigned short* Wt_l11 = (unsigned short*)alloc(320*256*2);
  unsigned short* Wt_l12 = (unsigned short*)alloc(256*256*2);
  unsigned short* Wt_l13 = (unsigned short*)alloc(256*256*2);
  unsigned short* Wt_l21 = (unsigned short*)alloc(320*256*2);
  unsigned short* Wt_l22 = (unsigned short*)alloc(256*256*2);
  unsigned short* Wt_l23 = (unsigned short*)alloc(256*256*2);
  if (off > ws_size) {
    fprintf(stderr, "[allegro] workspace too small: need %zu, have %zu\n", off, ws_size);
    return;
  }
  unsigned short* xb16 = (unsigned short*)xb;
  unsigned short* tp016 = (unsigned short*)tp0b;
  unsigned short* V16 = (unsigned short*)Vb;

  hipMemcpyAsync(t_val, tb.val,     sizeof(tb.val),     hipMemcpyHostToDevice, stream);
  hipMemcpyAsync(t_ij,  tb.ij,      sizeof(tb.ij),      hipMemcpyHostToDevice, stream);
  hipMemcpyAsync(t_pm,  tb.pmeta,   sizeof(tb.pmeta),   hipMemcpyHostToDevice, stream);
  hipMemcpyAsync(t_td,  tb.TD,      sizeof(tb.TD),      hipMemcpyHostToDevice, stream);
  hipMemcpyAsync(t_pr,  tb.pairs,   sizeof(tb.pairs),   hipMemcpyHostToDevice, stream);
  hipMemcpyAsync(t_oc,  tb.sl_origc,sizeof(tb.sl_origc),hipMemcpyHostToDevice, stream);

  const int s1b = tb.l3np[0];
  const int s1e = s1b + tb.l3np[1];
  const int s2e = s1e + tb.l3np[2];
  const int s3e = s2e + tb.l3np[3];

  {
    dim3 g((Kdim + 255)/256, 256);
    gbuild_k<<<g, 256, 0, stream>>>(t_td, W_v1, W_v2, W_v3, t_oc, Gt, Kdim,
                                    tb.npairs, s1b, s1e, s2e, s3e);
  }
  {
    WPack p;
    p.d[0] = { W_tb1, Wt_tb1,  72, 5 };
    p.d[1] = { W_tb2, Wt_tb2,  32, 6 };
    p.d[2] = { W_tb3, Wt_tb3,  64, 7 };
    p.d[3] = { W_tb4, Wt_tb4, 128, 8 };
    dim3 g(128, 4);
    wcvt_k<<<g, 256, 0, stream>>>(p);
  }
  {
    WPackT p;
    p.d[0] = { W_l11, Wt_l11, 320, 8 };
    p.d[1] = { W_l12, Wt_l12, 256, 8 };
    p.d[2] = { W_l13, Wt_l13, 256, 8 };
    p.d[3] = { W_l21, Wt_l21, 320, 8 };
    p.d[4] = { W_l22, Wt_l22, 256, 8 };
    p.d[5] = { W_l23, Wt_l23, 256, 8 };
    p.d[6] = { W_w2,  Wt_w2,  256, 4 };
    dim3 g(320, 7);
    wcvt_tile_k<<<g, 256, 0, stream>>>(p);
  }
  wcvt01_k<<<32, 256, 0, stream>>>(W_w0, W_w1, Wt_w01);
  sortprep_k<<<1, 1024, 0, stream>>>(senders, startsb, permb);

  // 1. edge features + Y + env  (x72 -> bufA fp32)
  edge_init_k<<<E_EDGES/256, 256, 0, stream>>>(vectors, senders, receivers, species,
                                               emb, envb, Yb, bufA);
  // 2+3. fused two-body MLP + w0/w1 + V init
  tb_fused_k<<<E_EDGES/64, 256, 0, stream>>>(bufA, Wt_tb1, Wt_tb2, Wt_tb3, Wt_tb4,
                                             Wt_w01, Yb, envb, xb16, V16, wb);

  // ---- layer 1 ----
  nodesum_k<<<NNODES, 256, 0, stream>>>(wb, Yb, permb, startsb, nodeb);
  vn_k<<<E_EDGES/VN_E, 512, 0, stream>>>(nodeb, V16, senders, vareps, t_pr, Gt,
                                         V16, Kdim, t_pm, t_ij, t_val, tp016);
  mlp3_k<0><<<E_EDGES/128, 512, 0, stream>>>(xb16, tp016, Wt_l11, Wt_l12, Wt_l13,
                                             xb16, envb, alpha, Wt_w2, wb,
                                             nullptr, nullptr, nullptr);

  // ---- layer 2 (lmax_out = 0): w2 already in wb from mlp3<0> ----
  nodesum_k<<<NNODES, 256, 0, stream>>>(wb, Yb, permb, startsb, nodeb);
  tp2_k<<<E_EDGES*64/256, 256, 0, stream>>>(nodeb, V16, senders, vareps, t_pm, t_ij,
                                            t_val, tp016);
  mlp3_k<1><<<E_EDGES/128, 512, 0, stream>>>(xb16, tp016, Wt_l21, Wt_l22, Wt_l23,
                                             nullptr, envb, alpha, nullptr, nullptr,
                                             W_h, W_out, (float*)d_out);
}